// Round 2
// baseline (1628.434 us; speedup 1.0000x reference)
//
#include <hip/hip_runtime.h>
#include <hip/hip_bf16.h>

#define D 128
#define NEG_SLOPE 0.2f

__device__ __forceinline__ float wave_reduce_sum(float v) {
#pragma unroll
    for (int m = 32; m >= 1; m >>= 1) v += __shfl_xor(v, m);
    return v;
}

// K1: h = x @ Wg ; a_src = h . att_src ; a_dst = h . att_dst
__global__ void k_gemm_h(const float* __restrict__ x, const float* __restrict__ Wg,
                         const float* __restrict__ att_src, const float* __restrict__ att_dst,
                         float* __restrict__ h, float* __restrict__ a_src, float* __restrict__ a_dst,
                         int N, int rows_per_block) {
    extern __shared__ float Wlds[]; // D*D floats
    const int tid = threadIdx.x;
    const float4* Wg4 = (const float4*)Wg;
    float4* Wl4 = (float4*)Wlds;
    for (int i = tid; i < D * D / 4; i += blockDim.x) Wl4[i] = Wg4[i];
    __syncthreads();
    const int wave = tid >> 6, lane = tid & 63;
    const int nwaves = blockDim.x >> 6;
    const float as0 = att_src[lane], as1 = att_src[lane + 64];
    const float ad0 = att_dst[lane], ad1 = att_dst[lane + 64];
    const int row0 = blockIdx.x * rows_per_block;
    for (int r = row0 + wave; r < row0 + rows_per_block && r < N; r += nwaves) {
        const float xr0 = x[(size_t)r * D + lane];
        const float xr1 = x[(size_t)r * D + lane + 64];
        float acc0 = 0.f, acc1 = 0.f;
#pragma unroll 8
        for (int k = 0; k < D; ++k) {
            float xv = __shfl((k < 64) ? xr0 : xr1, k & 63);
            acc0 += xv * Wlds[k * D + lane];
            acc1 += xv * Wlds[k * D + lane + 64];
        }
        h[(size_t)r * D + lane] = acc0;
        h[(size_t)r * D + lane + 64] = acc1;
        float s = wave_reduce_sum(acc0 * as0 + acc1 * as1);
        float t = wave_reduce_sum(acc0 * ad0 + acc1 * ad1);
        if (lane == 0) { a_src[r] = s; a_dst[r] = t; }
    }
}

// init h_gat rows to b_gat (bias added before scatter accumulation)
__global__ void k_init_hgat(float* __restrict__ hg, const float* __restrict__ b, int N) {
    int total = N * D;
    for (int i = blockIdx.x * blockDim.x + threadIdx.x; i < total; i += gridDim.x * blockDim.x)
        hg[i] = b[i & (D - 1)];
}

// K2: edge logits (with self loops) + encoded segment max
__global__ void k_edge_max(const int* __restrict__ ei, const float* __restrict__ a_src,
                           const float* __restrict__ a_dst, float* __restrict__ ebuf,
                           unsigned int* __restrict__ menc, int E, int N) {
    int tot = E + N;
    for (int i = blockIdx.x * blockDim.x + threadIdx.x; i < tot; i += gridDim.x * blockDim.x) {
        int s = (i < E) ? ei[i] : (i - E);
        int dt = (i < E) ? ei[E + i] : (i - E);
        float e = a_src[s] + a_dst[dt];
        e = (e > 0.f) ? e : NEG_SLOPE * e;
        ebuf[i] = e;
        int bi = __float_as_int(e);
        unsigned enc = (bi >= 0) ? ((unsigned)bi | 0x80000000u) : ~(unsigned)bi;
        atomicMax(menc + dt, enc);
    }
}

// K3a: p = exp(e - m[dst]); z[dst] += p
__global__ void k_edge_p(const int* __restrict__ ei, const unsigned int* __restrict__ menc,
                         float* __restrict__ ebuf, float* __restrict__ z, int E, int N) {
    int tot = E + N;
    for (int i = blockIdx.x * blockDim.x + threadIdx.x; i < tot; i += gridDim.x * blockDim.x) {
        int dt = (i < E) ? ei[E + i] : (i - E);
        unsigned u = menc[dt];
        float m = (u >= 0x80000000u) ? __int_as_float((int)(u ^ 0x80000000u))
                                     : __int_as_float((int)~u);
        float pv = expf(ebuf[i] - m);
        ebuf[i] = pv;
        atomicAdd(z + dt, pv);
    }
}

// K3b: h_gat[dst] += (p/z[dst]) * h[src]  — 2 edges per 256-thread block
__global__ void k_scatter_gat(const int* __restrict__ ei, const float* __restrict__ ebuf,
                              const float* __restrict__ z, const float* __restrict__ h,
                              float* __restrict__ hg, int E, int N) {
    int t = threadIdx.x;
    int i = blockIdx.x * 2 + (t >> 7);
    int f = t & 127;
    int tot = E + N;
    if (i >= tot) return;
    int s = (i < E) ? ei[i] : (i - E);
    int dt = (i < E) ? ei[E + i] : (i - E);
    float w = ebuf[i] / z[dt];
    atomicAdd(&hg[(size_t)dt * D + f], h[(size_t)s * D + f] * w);
}

// K4: agg[dst0] += h_gat[src0]; cnt[dst0] += 1   (original edges only)
__global__ void k_scatter_sage(const int* __restrict__ ei, const float* __restrict__ hg,
                               float* __restrict__ agg, float* __restrict__ cnt, int E) {
    int t = threadIdx.x;
    int i = blockIdx.x * 2 + (t >> 7);
    int f = t & 127;
    if (i >= E) return;
    int s = ei[i], dt = ei[E + i];
    atomicAdd(&agg[(size_t)dt * D + f], hg[(size_t)s * D + f]);
    if (f == 0) atomicAdd(cnt + dt, 1.0f);
}

// K5: out = normalize( (agg/cnt)@Wl + bl + hg@Wr )   (agg lives in d_out, overwritten)
__global__ void k_out(const float* __restrict__ cnt, const float* __restrict__ hg,
                      const float* __restrict__ Wl, const float* __restrict__ Wr,
                      const float* __restrict__ bl, float* __restrict__ out,
                      int N, int rows_per_block) {
    extern __shared__ float lds[]; // 2*D*D floats
    float* Al = lds;
    float* Ar = lds + D * D;
    const int tid = threadIdx.x;
    {
        const float4* s4 = (const float4*)Wl;
        float4* d4 = (float4*)Al;
        for (int i = tid; i < D * D / 4; i += blockDim.x) d4[i] = s4[i];
        s4 = (const float4*)Wr; d4 = (float4*)Ar;
        for (int i = tid; i < D * D / 4; i += blockDim.x) d4[i] = s4[i];
    }
    __syncthreads();
    const int wave = tid >> 6, lane = tid & 63, nw = blockDim.x >> 6;
    const float bl0 = bl[lane], bl1 = bl[lane + 64];
    const int row0 = blockIdx.x * rows_per_block;
    for (int r = row0 + wave; r < row0 + rows_per_block && r < N; r += nw) {
        float inv = 1.0f / fmaxf(cnt[r], 1.0f);
        float m0 = out[(size_t)r * D + lane] * inv;
        float m1 = out[(size_t)r * D + lane + 64] * inv;
        float g0 = hg[(size_t)r * D + lane];
        float g1 = hg[(size_t)r * D + lane + 64];
        float acc0 = bl0, acc1 = bl1;
#pragma unroll 4
        for (int k = 0; k < D; ++k) {
            float mv = __shfl((k < 64) ? m0 : m1, k & 63);
            float gv = __shfl((k < 64) ? g0 : g1, k & 63);
            acc0 += mv * Al[k * D + lane] + gv * Ar[k * D + lane];
            acc1 += mv * Al[k * D + lane + 64] + gv * Ar[k * D + lane + 64];
        }
        float ss = wave_reduce_sum(acc0 * acc0 + acc1 * acc1);
        float nrm = sqrtf(ss);
        float sc = 1.0f / fmaxf(nrm, 1e-12f);
        out[(size_t)r * D + lane] = acc0 * sc;
        out[(size_t)r * D + lane + 64] = acc1 * sc;
    }
}

extern "C" void kernel_launch(void* const* d_in, const int* in_sizes, int n_in,
                              void* d_out, int out_size, void* d_ws, size_t ws_size,
                              hipStream_t stream) {
    const float* x       = (const float*)d_in[0];
    const int*   ei      = (const int*)d_in[1];
    const float* Wg      = (const float*)d_in[2];
    const float* att_src = (const float*)d_in[3];
    const float* att_dst = (const float*)d_in[4];
    const float* bg      = (const float*)d_in[5];
    const float* Wl      = (const float*)d_in[6];
    const float* bl      = (const float*)d_in[7];
    const float* Wr      = (const float*)d_in[8];
    const int N = in_sizes[0] / D;
    const int E = in_sizes[1] / 2;
    const int tot = E + N;

    char* w = (char*)d_ws;
    float*    h     = (float*)w;       w += (size_t)N * D * 4;
    float*    hg    = (float*)w;       w += (size_t)N * D * 4;
    float*    a_src = (float*)w;       w += (size_t)N * 4;
    float*    a_dst = (float*)w;       w += (size_t)N * 4;
    unsigned* menc  = (unsigned*)w;    w += (size_t)N * 4;
    float*    z     = (float*)w;       w += (size_t)N * 4;
    float*    cnt   = (float*)w;       w += (size_t)N * 4;
    float*    ebuf  = (float*)w;       w += (size_t)tot * 4;
    float*    out_f = (float*)d_out;   // reused as agg scratch, overwritten by k_out

    (void)hipMemsetAsync(menc, 0, (size_t)N * 4, stream);
    (void)hipMemsetAsync(z, 0, (size_t)N * 4, stream);
    (void)hipMemsetAsync(cnt, 0, (size_t)N * 4, stream);
    (void)hipMemsetAsync(d_out, 0, (size_t)out_size * 4, stream);

    {   // K1: h, a_src, a_dst
        const int rpb = 32;
        int grid = (N + rpb - 1) / rpb;
        hipLaunchKernelGGL(k_gemm_h, dim3(grid), dim3(256), D * D * 4, stream,
                           x, Wg, att_src, att_dst, h, a_src, a_dst, N, rpb);
    }
    k_init_hgat<<<2048, 256, 0, stream>>>(hg, bg, N);
    k_edge_max<<<2048, 256, 0, stream>>>(ei, a_src, a_dst, ebuf, menc, E, N);
    k_edge_p<<<2048, 256, 0, stream>>>(ei, menc, ebuf, z, E, N);
    k_scatter_gat<<<(tot + 1) / 2, 256, 0, stream>>>(ei, ebuf, z, h, hg, E, N);
    k_scatter_sage<<<(E + 1) / 2, 256, 0, stream>>>(ei, hg, out_f, cnt, E);
    {   // K5: epilogue GEMMs + L2 normalize
        const int rpb = 32;
        int grid = (N + rpb - 1) / rpb;
        hipLaunchKernelGGL(k_out, dim3(grid), dim3(256), 2 * D * D * 4, stream,
                           cnt, hg, Wl, Wr, bl, out_f, N, rpb);
    }
}

// Round 3
// 362.962 us; speedup vs baseline: 4.4865x; 4.4865x over previous
//
#include <hip/hip_runtime.h>
#include <hip/hip_bf16.h>

#define D 128
#define NEG_SLOPE 0.2f
#define SCAN_BS 512

typedef __attribute__((ext_vector_type(8))) short short8;
typedef __attribute__((ext_vector_type(4))) float f32x4;

__device__ __forceinline__ float wave_reduce_sum(float v) {
#pragma unroll
    for (int m = 32; m >= 1; m >>= 1) v += __shfl_xor(v, m);
    return v;
}

__device__ __forceinline__ short f2bf(float f) {
    __hip_bfloat16 h = __float2bfloat16(f);
    return *reinterpret_cast<short*>(&h);
}

__device__ __forceinline__ short8 load_bf8(const float* p) {
    float4 p0 = *(const float4*)p;
    float4 p1 = *(const float4*)(p + 4);
    short8 r;
    r[0] = f2bf(p0.x); r[1] = f2bf(p0.y); r[2] = f2bf(p0.z); r[3] = f2bf(p0.w);
    r[4] = f2bf(p1.x); r[5] = f2bf(p1.y); r[6] = f2bf(p1.z); r[7] = f2bf(p1.w);
    return r;
}

// transpose + convert the three 128x128 weight mats to bf16 (WT[n][k] = W[k][n])
__global__ void k_wt(const float* __restrict__ Wg, const float* __restrict__ Wl,
                     const float* __restrict__ Wr, short* __restrict__ WgT,
                     short* __restrict__ WlT, short* __restrict__ WrT) {
    int i = blockIdx.x * blockDim.x + threadIdx.x;   // 0 .. 3*16384-1
    int m = i >> 14;
    int r = (i >> 7) & 127;
    int c = i & 127;
    const float* src = (m == 0) ? Wg : (m == 1) ? Wl : Wr;
    short* dst = (m == 0) ? WgT : (m == 1) ? WlT : WrT;
    dst[r * D + c] = f2bf(src[c * D + r]);
}

// ---- CSR build ----
__global__ void k_hist(const int* __restrict__ ei, int* __restrict__ cnt, int E) {
    int i = blockIdx.x * blockDim.x + threadIdx.x;
    if (i < E) atomicAdd(&cnt[ei[E + i]], 1);
}

__global__ void k_scan_block(const int* __restrict__ cnt, int* __restrict__ incl,
                             int* __restrict__ btot, int N) {
    __shared__ int s[SCAN_BS];
    int t = threadIdx.x, i = blockIdx.x * SCAN_BS + t;
    int v = (i < N) ? cnt[i] : 0;
    s[t] = v;
    __syncthreads();
    for (int d = 1; d < SCAN_BS; d <<= 1) {
        int u = (t >= d) ? s[t - d] : 0;
        __syncthreads();
        s[t] += u;
        __syncthreads();
    }
    if (i < N) incl[i] = s[t];
    if (t == SCAN_BS - 1) btot[blockIdx.x] = s[t];
}

__global__ void k_scan_tot(int* __restrict__ btot, int nb) {
    __shared__ int s[1024];
    int t = threadIdx.x;
    int v = (t < nb) ? btot[t] : 0;
    s[t] = v;
    __syncthreads();
    for (int d = 1; d < 1024; d <<= 1) {
        int u = (t >= d) ? s[t - d] : 0;
        __syncthreads();
        s[t] += u;
        __syncthreads();
    }
    if (t < nb) btot[t] = s[t] - v;  // exclusive base per block
}

__global__ void k_scan_add(const int* __restrict__ cnt, int* __restrict__ off,
                           const int* __restrict__ btot, int N) {
    int i = blockIdx.x * blockDim.x + threadIdx.x;
    if (i < N) off[i] = off[i] + btot[i / SCAN_BS] - cnt[i];  // incl -> excl + base
}

__global__ void k_bucket(const int* __restrict__ ei, const int* __restrict__ off,
                         int* __restrict__ fill, int* __restrict__ csr, int E) {
    int i = blockIdx.x * blockDim.x + threadIdx.x;
    if (i < E) {
        int dt = ei[E + i];
        int p = off[dt] + atomicAdd(&fill[dt], 1);
        csr[p] = ei[i];
    }
}

// ---- K1: h = x @ Wg (MFMA bf16), plus a_src = h.att_src, a_dst = h.att_dst ----
__global__ void k_gemm_h(const float* __restrict__ x, const short* __restrict__ WgT,
                         const float* __restrict__ att_src, const float* __restrict__ att_dst,
                         float* __restrict__ h, float* __restrict__ a_src,
                         float* __restrict__ a_dst, int N) {
    const int lane = threadIdx.x & 63;
    const int wave = threadIdx.x >> 6;
    const int r0 = blockIdx.x * 64 + wave * 16;
    const int lrow = lane & 15, lgrp = lane >> 4;
    const int arow = r0 + lrow;
    const bool ok = (arow < N);

    short8 afr[4];
    const float* xr = x + (size_t)arow * D + lgrp * 8;
#pragma unroll
    for (int kt = 0; kt < 4; ++kt) {
        if (ok) afr[kt] = load_bf8(xr + kt * 32);
        else { short8 zf; for (int j = 0; j < 8; ++j) zf[j] = 0; afr[kt] = zf; }
    }

    f32x4 acc[8];
#pragma unroll
    for (int f = 0; f < 8; ++f) acc[f] = (f32x4){0.f, 0.f, 0.f, 0.f};
#pragma unroll
    for (int f = 0; f < 8; ++f) {
        const short* wb = WgT + ((f * 16 + lrow) * D + lgrp * 8);
#pragma unroll
        for (int kt = 0; kt < 4; ++kt) {
            short8 b = *(const short8*)(wb + kt * 32);
            acc[f] = __builtin_amdgcn_mfma_f32_16x16x32_bf16(afr[kt], b, acc[f], 0, 0, 0);
        }
    }

    float ps[4] = {0.f, 0.f, 0.f, 0.f}, pd[4] = {0.f, 0.f, 0.f, 0.f};
    const int rbase = r0 + lgrp * 4;
#pragma unroll
    for (int f = 0; f < 8; ++f) {
        int col = f * 16 + lrow;
        float as = att_src[col], ad = att_dst[col];
#pragma unroll
        for (int j = 0; j < 4; ++j) {
            float v = acc[f][j];
            if (rbase + j < N) h[(size_t)(rbase + j) * D + col] = v;
            ps[j] += v * as;
            pd[j] += v * ad;
        }
    }
#pragma unroll
    for (int m = 8; m >= 1; m >>= 1)
#pragma unroll
        for (int j = 0; j < 4; ++j) {
            ps[j] += __shfl_xor(ps[j], m);
            pd[j] += __shfl_xor(pd[j], m);
        }
    if (lrow == 0) {
#pragma unroll
        for (int j = 0; j < 4; ++j)
            if (rbase + j < N) { a_src[rbase + j] = ps[j]; a_dst[rbase + j] = pd[j]; }
    }
}

// ---- GAT aggregation: one wave per dst node, CSR gather, no atomics ----
__global__ void k_attn(const int* __restrict__ csr, const int* __restrict__ off,
                       const int* __restrict__ cnt, const float* __restrict__ a_src,
                       const float* __restrict__ a_dst, const float* __restrict__ h,
                       const float* __restrict__ bg, float* __restrict__ hg, int N) {
    const int lane = threadIdx.x & 63;
    const int d = blockIdx.x * (blockDim.x >> 6) + (threadIdx.x >> 6);
    if (d >= N) return;
    const int deg = cnt[d], o = off[d];
    const float ad = a_dst[d];
    float es = a_src[d] + ad;
    es = (es > 0.f) ? es : NEG_SLOPE * es;
    float m = es;
    for (int i = lane; i < deg; i += 64) {
        float e = a_src[csr[o + i]] + ad;
        e = (e > 0.f) ? e : NEG_SLOPE * e;
        m = fmaxf(m, e);
    }
#pragma unroll
    for (int mm = 32; mm >= 1; mm >>= 1) m = fmaxf(m, __shfl_xor(m, mm));
    float zz = (lane == 0) ? expf(es - m) : 0.f;
    for (int i = lane; i < deg; i += 64) {
        float e = a_src[csr[o + i]] + ad;
        e = (e > 0.f) ? e : NEG_SLOPE * e;
        zz += expf(e - m);
    }
    zz = wave_reduce_sum(zz);
    const float inv = 1.f / zz;
    float al = expf(es - m) * inv;
    float acc0 = al * h[(size_t)d * D + lane];
    float acc1 = al * h[(size_t)d * D + lane + 64];
    for (int i = 0; i < deg; ++i) {
        int s = csr[o + i];
        float e = a_src[s] + ad;
        e = (e > 0.f) ? e : NEG_SLOPE * e;
        float a2 = expf(e - m) * inv;
        acc0 += a2 * h[(size_t)s * D + lane];
        acc1 += a2 * h[(size_t)s * D + lane + 64];
    }
    hg[(size_t)d * D + lane] = acc0 + bg[lane];
    hg[(size_t)d * D + lane + 64] = acc1 + bg[lane + 64];
}

// ---- SAGE mean aggregation: one wave per node ----
__global__ void k_sage(const int* __restrict__ csr, const int* __restrict__ off,
                       const int* __restrict__ cnt, const float* __restrict__ hg,
                       float* __restrict__ mean, int N) {
    const int lane = threadIdx.x & 63;
    const int d = blockIdx.x * (blockDim.x >> 6) + (threadIdx.x >> 6);
    if (d >= N) return;
    const int deg = cnt[d], o = off[d];
    float a0 = 0.f, a1 = 0.f;
    for (int i = 0; i < deg; ++i) {
        int s = csr[o + i];
        a0 += hg[(size_t)s * D + lane];
        a1 += hg[(size_t)s * D + lane + 64];
    }
    const float inv = 1.f / fmaxf((float)deg, 1.f);
    mean[(size_t)d * D + lane] = a0 * inv;
    mean[(size_t)d * D + lane + 64] = a1 * inv;
}

// ---- out = normalize(mean@Wl + bl + hg@Wr) via MFMA bf16 ----
__global__ void k_out(const float* __restrict__ mean, const float* __restrict__ hg,
                      const short* __restrict__ WlT, const short* __restrict__ WrT,
                      const float* __restrict__ bl, float* __restrict__ out, int N) {
    const int lane = threadIdx.x & 63;
    const int wave = threadIdx.x >> 6;
    const int r0 = blockIdx.x * 64 + wave * 16;
    const int lrow = lane & 15, lgrp = lane >> 4;
    const int arow = r0 + lrow;
    const bool ok = (arow < N);

    short8 am[4], ah[4];
    const float* mp = mean + (size_t)arow * D + lgrp * 8;
    const float* hp = hg + (size_t)arow * D + lgrp * 8;
#pragma unroll
    for (int kt = 0; kt < 4; ++kt) {
        if (ok) {
            am[kt] = load_bf8(mp + kt * 32);
            ah[kt] = load_bf8(hp + kt * 32);
        } else {
            short8 zf; for (int j = 0; j < 8; ++j) zf[j] = 0;
            am[kt] = zf; ah[kt] = zf;
        }
    }

    f32x4 acc[8];
#pragma unroll
    for (int f = 0; f < 8; ++f) {
        float b = bl[f * 16 + lrow];
        acc[f] = (f32x4){b, b, b, b};
    }
#pragma unroll
    for (int f = 0; f < 8; ++f) {
        const short* wl = WlT + ((f * 16 + lrow) * D + lgrp * 8);
        const short* wr = WrT + ((f * 16 + lrow) * D + lgrp * 8);
#pragma unroll
        for (int kt = 0; kt < 4; ++kt) {
            short8 b0 = *(const short8*)(wl + kt * 32);
            acc[f] = __builtin_amdgcn_mfma_f32_16x16x32_bf16(am[kt], b0, acc[f], 0, 0, 0);
            short8 b1 = *(const short8*)(wr + kt * 32);
            acc[f] = __builtin_amdgcn_mfma_f32_16x16x32_bf16(ah[kt], b1, acc[f], 0, 0, 0);
        }
    }

    float ss[4] = {0.f, 0.f, 0.f, 0.f};
#pragma unroll
    for (int f = 0; f < 8; ++f)
#pragma unroll
        for (int j = 0; j < 4; ++j) ss[j] += acc[f][j] * acc[f][j];
#pragma unroll
    for (int m = 8; m >= 1; m >>= 1)
#pragma unroll
        for (int j = 0; j < 4; ++j) ss[j] += __shfl_xor(ss[j], m);

    const int rbase = r0 + lgrp * 4;
#pragma unroll
    for (int j = 0; j < 4; ++j) {
        int r = rbase + j;
        if (r < N) {
            float sc = 1.f / fmaxf(sqrtf(ss[j]), 1e-12f);
#pragma unroll
            for (int f = 0; f < 8; ++f)
                out[(size_t)r * D + f * 16 + lrow] = acc[f][j] * sc;
        }
    }
}

extern "C" void kernel_launch(void* const* d_in, const int* in_sizes, int n_in,
                              void* d_out, int out_size, void* d_ws, size_t ws_size,
                              hipStream_t stream) {
    const float* x       = (const float*)d_in[0];
    const int*   ei      = (const int*)d_in[1];
    const float* Wg      = (const float*)d_in[2];
    const float* att_src = (const float*)d_in[3];
    const float* att_dst = (const float*)d_in[4];
    const float* bg      = (const float*)d_in[5];
    const float* Wl      = (const float*)d_in[6];
    const float* bl      = (const float*)d_in[7];
    const float* Wr      = (const float*)d_in[8];
    const int N = in_sizes[0] / D;
    const int E = in_sizes[1] / 2;

    char* w = (char*)d_ws;
    float* h     = (float*)w;  w += (size_t)N * D * 4;   // reused as `mean` after k_attn
    float* hg    = (float*)w;  w += (size_t)N * D * 4;
    float* a_src = (float*)w;  w += (size_t)N * 4;
    float* a_dst = (float*)w;  w += (size_t)N * 4;
    int*   cnt_i = (int*)w;    w += (size_t)N * 4;
    int*   off   = (int*)w;    w += (size_t)N * 4;
    int*   fill  = (int*)w;    w += (size_t)N * 4;
    int*   btot  = (int*)w;    w += 1024 * 4;
    int*   csr   = (int*)w;    w += (size_t)E * 4;
    short* WgT   = (short*)w;  w += (size_t)D * D * 2;
    short* WlT   = (short*)w;  w += (size_t)D * D * 2;
    short* WrT   = (short*)w;  w += (size_t)D * D * 2;
    float* mean  = h;
    float* out_f = (float*)d_out;

    (void)hipMemsetAsync(cnt_i, 0, (size_t)N * 4, stream);
    (void)hipMemsetAsync(fill, 0, (size_t)N * 4, stream);

    const int nb = (N + SCAN_BS - 1) / SCAN_BS;   // 196 <= 1024

    k_wt<<<(3 * D * D) / 256, 256, 0, stream>>>(Wg, Wl, Wr, WgT, WlT, WrT);
    k_hist<<<(E + 255) / 256, 256, 0, stream>>>(ei, cnt_i, E);
    k_scan_block<<<nb, SCAN_BS, 0, stream>>>(cnt_i, off, btot, N);
    k_scan_tot<<<1, 1024, 0, stream>>>(btot, nb);
    k_scan_add<<<(N + 255) / 256, 256, 0, stream>>>(cnt_i, off, btot, N);
    k_bucket<<<(E + 255) / 256, 256, 0, stream>>>(ei, off, fill, csr, E);

    k_gemm_h<<<(N + 63) / 64, 256, 0, stream>>>(x, WgT, att_src, att_dst, h, a_src, a_dst, N);
    k_attn<<<(N + 3) / 4, 256, 0, stream>>>(csr, off, cnt_i, a_src, a_dst, h, bg, hg, N);
    k_sage<<<(N + 3) / 4, 256, 0, stream>>>(csr, off, cnt_i, hg, mean, N);
    k_out<<<(N + 63) / 64, 256, 0, stream>>>(mean, hg, WlT, WrT, bl, out_f, N);
}

// Round 4
// 292.500 us; speedup vs baseline: 5.5673x; 1.2409x over previous
//
#include <hip/hip_runtime.h>
#include <hip/hip_bf16.h>

#define D 128
#define NEG_SLOPE 0.2f
#define SCAN_BS 512

typedef __attribute__((ext_vector_type(8))) short short8;
typedef __attribute__((ext_vector_type(4))) float f32x4;

__device__ __forceinline__ float wave_reduce_sum(float v) {
#pragma unroll
    for (int m = 32; m >= 1; m >>= 1) v += __shfl_xor(v, m);
    return v;
}

__device__ __forceinline__ unsigned short f2bfu(float f) {
    __hip_bfloat16 h = __float2bfloat16(f);
    return *reinterpret_cast<unsigned short*>(&h);
}

__device__ __forceinline__ float bf2f(unsigned short u) {
    return __uint_as_float(((unsigned)u) << 16);
}

__device__ __forceinline__ short8 load_bf8(const float* p) {
    float4 p0 = *(const float4*)p;
    float4 p1 = *(const float4*)(p + 4);
    short8 r;
    r[0] = (short)f2bfu(p0.x); r[1] = (short)f2bfu(p0.y);
    r[2] = (short)f2bfu(p0.z); r[3] = (short)f2bfu(p0.w);
    r[4] = (short)f2bfu(p1.x); r[5] = (short)f2bfu(p1.y);
    r[6] = (short)f2bfu(p1.z); r[7] = (short)f2bfu(p1.w);
    return r;
}

// transpose + convert the three 128x128 weight mats to bf16 (WT[n][k] = W[k][n])
__global__ void k_wt(const float* __restrict__ Wg, const float* __restrict__ Wl,
                     const float* __restrict__ Wr, short* __restrict__ WgT,
                     short* __restrict__ WlT, short* __restrict__ WrT) {
    int i = blockIdx.x * blockDim.x + threadIdx.x;
    int m = i >> 14;
    int r = (i >> 7) & 127;
    int c = i & 127;
    const float* src = (m == 0) ? Wg : (m == 1) ? Wl : Wr;
    short* dst = (m == 0) ? WgT : (m == 1) ? WlT : WrT;
    dst[r * D + c] = (short)f2bfu(src[c * D + r]);
}

// ---- CSR build ----
__global__ void k_hist(const int* __restrict__ ei, int* __restrict__ cnt, int E) {
    int i = blockIdx.x * blockDim.x + threadIdx.x;
    if (i < E) atomicAdd(&cnt[ei[E + i]], 1);
}

__global__ void k_scan_block(const int* __restrict__ cnt, int* __restrict__ incl,
                             int* __restrict__ btot, int N) {
    __shared__ int s[SCAN_BS];
    int t = threadIdx.x, i = blockIdx.x * SCAN_BS + t;
    int v = (i < N) ? cnt[i] : 0;
    s[t] = v;
    __syncthreads();
    for (int d = 1; d < SCAN_BS; d <<= 1) {
        int u = (t >= d) ? s[t - d] : 0;
        __syncthreads();
        s[t] += u;
        __syncthreads();
    }
    if (i < N) incl[i] = s[t];
    if (t == SCAN_BS - 1) btot[blockIdx.x] = s[t];
}

__global__ void k_scan_tot(int* __restrict__ btot, int nb) {
    __shared__ int s[1024];
    int t = threadIdx.x;
    int v = (t < nb) ? btot[t] : 0;
    s[t] = v;
    __syncthreads();
    for (int d = 1; d < 1024; d <<= 1) {
        int u = (t >= d) ? s[t - d] : 0;
        __syncthreads();
        s[t] += u;
        __syncthreads();
    }
    if (t < nb) btot[t] = s[t] - v;
}

__global__ void k_scan_add(const int* __restrict__ cnt, int* __restrict__ off,
                           const int* __restrict__ btot, int N) {
    int i = blockIdx.x * blockDim.x + threadIdx.x;
    if (i < N) off[i] = off[i] + btot[i / SCAN_BS] - cnt[i];
}

__global__ void k_bucket(const int* __restrict__ ei, const int* __restrict__ off,
                         int* __restrict__ fill, int* __restrict__ csr, int E) {
    int i = blockIdx.x * blockDim.x + threadIdx.x;
    if (i < E) {
        int dt = ei[E + i];
        int p = off[dt] + atomicAdd(&fill[dt], 1);
        csr[p] = ei[i];
    }
}

// ---- K1: h = x @ Wg (MFMA bf16) -> h_bf; a_src = h.att_src; a_dst = h.att_dst ----
__global__ void k_gemm_h(const float* __restrict__ x, const short* __restrict__ WgT,
                         const float* __restrict__ att_src, const float* __restrict__ att_dst,
                         unsigned short* __restrict__ h_bf, float* __restrict__ a_src,
                         float* __restrict__ a_dst, int N) {
    const int lane = threadIdx.x & 63;
    const int wave = threadIdx.x >> 6;
    const int r0 = blockIdx.x * 64 + wave * 16;
    const int lrow = lane & 15, lgrp = lane >> 4;
    const int arow = r0 + lrow;
    const bool ok = (arow < N);

    short8 afr[4];
    const float* xr = x + (size_t)arow * D + lgrp * 8;
#pragma unroll
    for (int kt = 0; kt < 4; ++kt) {
        if (ok) afr[kt] = load_bf8(xr + kt * 32);
        else { short8 zf; for (int j = 0; j < 8; ++j) zf[j] = 0; afr[kt] = zf; }
    }

    f32x4 acc[8];
#pragma unroll
    for (int f = 0; f < 8; ++f) acc[f] = (f32x4){0.f, 0.f, 0.f, 0.f};
#pragma unroll
    for (int f = 0; f < 8; ++f) {
        const short* wb = WgT + ((f * 16 + lrow) * D + lgrp * 8);
#pragma unroll
        for (int kt = 0; kt < 4; ++kt) {
            short8 b = *(const short8*)(wb + kt * 32);
            acc[f] = __builtin_amdgcn_mfma_f32_16x16x32_bf16(afr[kt], b, acc[f], 0, 0, 0);
        }
    }

    float ps[4] = {0.f, 0.f, 0.f, 0.f}, pd[4] = {0.f, 0.f, 0.f, 0.f};
    const int rbase = r0 + lgrp * 4;
#pragma unroll
    for (int f = 0; f < 8; ++f) {
        int col = f * 16 + lrow;
        float as = att_src[col], ad = att_dst[col];
#pragma unroll
        for (int j = 0; j < 4; ++j) {
            float v = acc[f][j];
            if (rbase + j < N) h_bf[(size_t)(rbase + j) * D + col] = f2bfu(v);
            ps[j] += v * as;
            pd[j] += v * ad;
        }
    }
#pragma unroll
    for (int m = 8; m >= 1; m >>= 1)
#pragma unroll
        for (int j = 0; j < 4; ++j) {
            ps[j] += __shfl_xor(ps[j], m);
            pd[j] += __shfl_xor(pd[j], m);
        }
    if (lrow == 0) {
#pragma unroll
        for (int j = 0; j < 4; ++j)
            if (rbase + j < N) { a_src[rbase + j] = ps[j]; a_dst[rbase + j] = pd[j]; }
    }
}

// ---- GAT aggregation: one wave per dst node; per-edge state in registers ----
__global__ void k_attn(const int* __restrict__ csr, const int* __restrict__ off,
                       const int* __restrict__ cnt, const float* __restrict__ a_src,
                       const float* __restrict__ a_dst, const unsigned short* __restrict__ h_bf,
                       const float* __restrict__ bg, unsigned short* __restrict__ hg_bf, int N) {
    const int lane = threadIdx.x & 63;
    const int d = blockIdx.x * (blockDim.x >> 6) + (threadIdx.x >> 6);
    if (d >= N) return;
    const int deg = cnt[d], o = off[d];
    const int e2 = lane * 2;
    const float ad = a_dst[d];
    float es = a_src[d] + ad;
    es = (es > 0.f) ? es : NEG_SLOPE * es;
    float acc0, acc1, inv;

    if (deg <= 64) {
        int sv = 0;
        float e = -INFINITY;
        if (lane < deg) {
            sv = csr[o + lane];
            float t = a_src[sv] + ad;
            e = (t > 0.f) ? t : NEG_SLOPE * t;
        }
        float mx = e;
#pragma unroll
        for (int mm = 32; mm >= 1; mm >>= 1) mx = fmaxf(mx, __shfl_xor(mx, mm));
        mx = fmaxf(mx, es);
        float p = (lane < deg) ? expf(e - mx) : 0.f;
        float ps = expf(es - mx);
        float z = wave_reduce_sum(p) + ps;
        inv = 1.f / z;
        ushort2 hv = *(const ushort2*)(h_bf + (size_t)d * D + e2);
        acc0 = ps * bf2f(hv.x);
        acc1 = ps * bf2f(hv.y);
        for (int i = 0; i < deg; ++i) {
            int s = __shfl(sv, i);
            float pi = __shfl(p, i);
            ushort2 hh = *(const ushort2*)(h_bf + (size_t)s * D + e2);
            acc0 += pi * bf2f(hh.x);
            acc1 += pi * bf2f(hh.y);
        }
    } else {  // rare fallback
        float mx = es;
        for (int i = lane; i < deg; i += 64) {
            float t = a_src[csr[o + i]] + ad;
            t = (t > 0.f) ? t : NEG_SLOPE * t;
            mx = fmaxf(mx, t);
        }
#pragma unroll
        for (int mm = 32; mm >= 1; mm >>= 1) mx = fmaxf(mx, __shfl_xor(mx, mm));
        float zp = 0.f;
        for (int i = lane; i < deg; i += 64) {
            float t = a_src[csr[o + i]] + ad;
            t = (t > 0.f) ? t : NEG_SLOPE * t;
            zp += expf(t - mx);
        }
        float ps = expf(es - mx);
        float z = wave_reduce_sum(zp) + ps;
        inv = 1.f / z;
        ushort2 hv = *(const ushort2*)(h_bf + (size_t)d * D + e2);
        acc0 = ps * bf2f(hv.x);
        acc1 = ps * bf2f(hv.y);
        for (int i = 0; i < deg; ++i) {
            int s = csr[o + i];
            float t = a_src[s] + ad;
            t = (t > 0.f) ? t : NEG_SLOPE * t;
            float pi = expf(t - mx);
            ushort2 hh = *(const ushort2*)(h_bf + (size_t)s * D + e2);
            acc0 += pi * bf2f(hh.x);
            acc1 += pi * bf2f(hh.y);
        }
    }
    acc0 = acc0 * inv + bg[e2];
    acc1 = acc1 * inv + bg[e2 + 1];
    ushort2 r;
    r.x = f2bfu(acc0);
    r.y = f2bfu(acc1);
    *(ushort2*)(hg_bf + (size_t)d * D + e2) = r;
}

// ---- SAGE mean aggregation: one wave per node ----
__global__ void k_sage(const int* __restrict__ csr, const int* __restrict__ off,
                       const int* __restrict__ cnt, const unsigned short* __restrict__ hg_bf,
                       unsigned short* __restrict__ mean_bf, int N) {
    const int lane = threadIdx.x & 63;
    const int d = blockIdx.x * (blockDim.x >> 6) + (threadIdx.x >> 6);
    if (d >= N) return;
    const int deg = cnt[d], o = off[d];
    const int e2 = lane * 2;
    float a0 = 0.f, a1 = 0.f;
    if (deg <= 64) {
        int sv = 0;
        if (lane < deg) sv = csr[o + lane];
        for (int i = 0; i < deg; ++i) {
            int s = __shfl(sv, i);
            ushort2 hh = *(const ushort2*)(hg_bf + (size_t)s * D + e2);
            a0 += bf2f(hh.x);
            a1 += bf2f(hh.y);
        }
    } else {
        for (int i = 0; i < deg; ++i) {
            int s = csr[o + i];
            ushort2 hh = *(const ushort2*)(hg_bf + (size_t)s * D + e2);
            a0 += bf2f(hh.x);
            a1 += bf2f(hh.y);
        }
    }
    const float inv = 1.f / fmaxf((float)deg, 1.f);
    ushort2 r;
    r.x = f2bfu(a0 * inv);
    r.y = f2bfu(a1 * inv);
    *(ushort2*)(mean_bf + (size_t)d * D + e2) = r;
}

// ---- out = normalize(mean@Wl + bl + hg@Wr) via MFMA bf16 ----
__global__ void k_out(const unsigned short* __restrict__ mean_bf,
                      const unsigned short* __restrict__ hg_bf,
                      const short* __restrict__ WlT, const short* __restrict__ WrT,
                      const float* __restrict__ bl, float* __restrict__ out, int N) {
    const int lane = threadIdx.x & 63;
    const int wave = threadIdx.x >> 6;
    const int r0 = blockIdx.x * 64 + wave * 16;
    const int lrow = lane & 15, lgrp = lane >> 4;
    const int arow = r0 + lrow;
    const bool ok = (arow < N);

    short8 am[4], ah[4];
    const unsigned short* mp = mean_bf + (size_t)arow * D + lgrp * 8;
    const unsigned short* hp = hg_bf + (size_t)arow * D + lgrp * 8;
#pragma unroll
    for (int kt = 0; kt < 4; ++kt) {
        if (ok) {
            am[kt] = *(const short8*)(mp + kt * 32);
            ah[kt] = *(const short8*)(hp + kt * 32);
        } else {
            short8 zf; for (int j = 0; j < 8; ++j) zf[j] = 0;
            am[kt] = zf; ah[kt] = zf;
        }
    }

    f32x4 acc[8];
#pragma unroll
    for (int f = 0; f < 8; ++f) {
        float b = bl[f * 16 + lrow];
        acc[f] = (f32x4){b, b, b, b};
    }
#pragma unroll
    for (int f = 0; f < 8; ++f) {
        const short* wl = WlT + ((f * 16 + lrow) * D + lgrp * 8);
        const short* wr = WrT + ((f * 16 + lrow) * D + lgrp * 8);
#pragma unroll
        for (int kt = 0; kt < 4; ++kt) {
            short8 b0 = *(const short8*)(wl + kt * 32);
            acc[f] = __builtin_amdgcn_mfma_f32_16x16x32_bf16(am[kt], b0, acc[f], 0, 0, 0);
            short8 b1 = *(const short8*)(wr + kt * 32);
            acc[f] = __builtin_amdgcn_mfma_f32_16x16x32_bf16(ah[kt], b1, acc[f], 0, 0, 0);
        }
    }

    float ss[4] = {0.f, 0.f, 0.f, 0.f};
#pragma unroll
    for (int f = 0; f < 8; ++f)
#pragma unroll
        for (int j = 0; j < 4; ++j) ss[j] += acc[f][j] * acc[f][j];
#pragma unroll
    for (int m = 8; m >= 1; m >>= 1)
#pragma unroll
        for (int j = 0; j < 4; ++j) ss[j] += __shfl_xor(ss[j], m);

    const int rbase = r0 + lgrp * 4;
#pragma unroll
    for (int j = 0; j < 4; ++j) {
        int r = rbase + j;
        if (r < N) {
            float sc = 1.f / fmaxf(sqrtf(ss[j]), 1e-12f);
#pragma unroll
            for (int f = 0; f < 8; ++f)
                out[(size_t)r * D + f * 16 + lrow] = acc[f][j] * sc;
        }
    }
}

extern "C" void kernel_launch(void* const* d_in, const int* in_sizes, int n_in,
                              void* d_out, int out_size, void* d_ws, size_t ws_size,
                              hipStream_t stream) {
    const float* x       = (const float*)d_in[0];
    const int*   ei      = (const int*)d_in[1];
    const float* Wg      = (const float*)d_in[2];
    const float* att_src = (const float*)d_in[3];
    const float* att_dst = (const float*)d_in[4];
    const float* bg      = (const float*)d_in[5];
    const float* Wl      = (const float*)d_in[6];
    const float* bl      = (const float*)d_in[7];
    const float* Wr      = (const float*)d_in[8];
    const int N = in_sizes[0] / D;
    const int E = in_sizes[1] / 2;

    char* w = (char*)d_ws;
    unsigned short* h_bf    = (unsigned short*)w;  w += (size_t)N * D * 2;
    unsigned short* hg_bf   = (unsigned short*)w;  w += (size_t)N * D * 2;
    unsigned short* mean_bf = (unsigned short*)w;  w += (size_t)N * D * 2;
    float* a_src = (float*)w;  w += (size_t)N * 4;
    float* a_dst = (float*)w;  w += (size_t)N * 4;
    int*   cnt_i = (int*)w;    w += (size_t)N * 4;
    int*   off   = (int*)w;    w += (size_t)N * 4;
    int*   fill  = (int*)w;    w += (size_t)N * 4;
    int*   btot  = (int*)w;    w += 1024 * 4;
    int*   csr   = (int*)w;    w += (size_t)E * 4;
    short* WgT   = (short*)w;  w += (size_t)D * D * 2;
    short* WlT   = (short*)w;  w += (size_t)D * D * 2;
    short* WrT   = (short*)w;  w += (size_t)D * D * 2;
    float* out_f = (float*)d_out;

    (void)hipMemsetAsync(cnt_i, 0, (size_t)N * 4, stream);
    (void)hipMemsetAsync(fill, 0, (size_t)N * 4, stream);

    const int nb = (N + SCAN_BS - 1) / SCAN_BS;

    k_wt<<<(3 * D * D) / 256, 256, 0, stream>>>(Wg, Wl, Wr, WgT, WlT, WrT);
    k_hist<<<(E + 255) / 256, 256, 0, stream>>>(ei, cnt_i, E);
    k_scan_block<<<nb, SCAN_BS, 0, stream>>>(cnt_i, off, btot, N);
    k_scan_tot<<<1, 1024, 0, stream>>>(btot, nb);
    k_scan_add<<<(N + 255) / 256, 256, 0, stream>>>(cnt_i, off, btot, N);
    k_bucket<<<(E + 255) / 256, 256, 0, stream>>>(ei, off, fill, csr, E);

    k_gemm_h<<<(N + 63) / 64, 256, 0, stream>>>(x, WgT, att_src, att_dst, h_bf, a_src, a_dst, N);
    k_attn<<<(N + 3) / 4, 256, 0, stream>>>(csr, off, cnt_i, a_src, a_dst, h_bf, bg, hg_bf, N);
    k_sage<<<(N + 3) / 4, 256, 0, stream>>>(csr, off, cnt_i, hg_bf, mean_bf, N);
    k_out<<<(N + 63) / 64, 256, 0, stream>>>(mean_bf, hg_bf, WlT, WrT, bl, out_f, N);
}

// Round 5
// 254.270 us; speedup vs baseline: 6.4043x; 1.1504x over previous
//
#include <hip/hip_runtime.h>
#include <hip/hip_bf16.h>

#define D 128
#define NEG_SLOPE 0.2f
#define SCAN_BS 512

typedef __attribute__((ext_vector_type(8))) short short8;
typedef __attribute__((ext_vector_type(4))) float f32x4;

__device__ __forceinline__ float group_max16(float v) {
#pragma unroll
    for (int m = 8; m >= 1; m >>= 1) v = fmaxf(v, __shfl_xor(v, m));
    return v;
}
__device__ __forceinline__ float group_sum16(float v) {
#pragma unroll
    for (int m = 8; m >= 1; m >>= 1) v += __shfl_xor(v, m);
    return v;
}

__device__ __forceinline__ unsigned short f2bfu(float f) {
    __hip_bfloat16 h = __float2bfloat16(f);
    return *reinterpret_cast<unsigned short*>(&h);
}

__device__ __forceinline__ float bf2f(unsigned short u) {
    return __uint_as_float(((unsigned)u) << 16);
}

__device__ __forceinline__ short8 load_bf8(const float* p) {
    float4 p0 = *(const float4*)p;
    float4 p1 = *(const float4*)(p + 4);
    short8 r;
    r[0] = (short)f2bfu(p0.x); r[1] = (short)f2bfu(p0.y);
    r[2] = (short)f2bfu(p0.z); r[3] = (short)f2bfu(p0.w);
    r[4] = (short)f2bfu(p1.x); r[5] = (short)f2bfu(p1.y);
    r[6] = (short)f2bfu(p1.z); r[7] = (short)f2bfu(p1.w);
    return r;
}

// transpose + convert the three 128x128 weight mats to bf16 (WT[n][k] = W[k][n])
__global__ void k_wt(const float* __restrict__ Wg, const float* __restrict__ Wl,
                     const float* __restrict__ Wr, short* __restrict__ WgT,
                     short* __restrict__ WlT, short* __restrict__ WrT) {
    int i = blockIdx.x * blockDim.x + threadIdx.x;
    int m = i >> 14;
    int r = (i >> 7) & 127;
    int c = i & 127;
    const float* src = (m == 0) ? Wg : (m == 1) ? Wl : Wr;
    short* dst = (m == 0) ? WgT : (m == 1) ? WlT : WrT;
    dst[r * D + c] = (short)f2bfu(src[c * D + r]);
}

// ---- CSR build ----
__global__ void k_hist(const int* __restrict__ ei, int* __restrict__ cnt, int E) {
    int i = blockIdx.x * blockDim.x + threadIdx.x;
    if (i < E) atomicAdd(&cnt[ei[E + i]], 1);
}

__global__ void k_scan_block(const int* __restrict__ cnt, int* __restrict__ incl,
                             int* __restrict__ btot, int N) {
    __shared__ int s[SCAN_BS];
    int t = threadIdx.x, i = blockIdx.x * SCAN_BS + t;
    int v = (i < N) ? cnt[i] : 0;
    s[t] = v;
    __syncthreads();
    for (int d = 1; d < SCAN_BS; d <<= 1) {
        int u = (t >= d) ? s[t - d] : 0;
        __syncthreads();
        s[t] += u;
        __syncthreads();
    }
    if (i < N) incl[i] = s[t];
    if (t == SCAN_BS - 1) btot[blockIdx.x] = s[t];
}

__global__ void k_scan_tot(int* __restrict__ btot, int nb) {
    __shared__ int s[1024];
    int t = threadIdx.x;
    int v = (t < nb) ? btot[t] : 0;
    s[t] = v;
    __syncthreads();
    for (int d = 1; d < 1024; d <<= 1) {
        int u = (t >= d) ? s[t - d] : 0;
        __syncthreads();
        s[t] += u;
        __syncthreads();
    }
    if (t < nb) btot[t] = s[t] - v;
}

__global__ void k_scan_add(const int* __restrict__ cnt, int* __restrict__ off,
                           const int* __restrict__ btot, int N) {
    int i = blockIdx.x * blockDim.x + threadIdx.x;
    if (i < N) off[i] = off[i] + btot[i / SCAN_BS] - cnt[i];
}

__global__ void k_bucket(const int* __restrict__ ei, const int* __restrict__ off,
                         int* __restrict__ fill, int* __restrict__ csr, int E) {
    int i = blockIdx.x * blockDim.x + threadIdx.x;
    if (i < E) {
        int dt = ei[E + i];
        int p = off[dt] + atomicAdd(&fill[dt], 1);
        csr[p] = ei[i];
    }
}

// ---- K1: h = x @ Wg (MFMA bf16) -> h_bf; a_src = h.att_src; a_dst = h.att_dst ----
__global__ void k_gemm_h(const float* __restrict__ x, const short* __restrict__ WgT,
                         const float* __restrict__ att_src, const float* __restrict__ att_dst,
                         unsigned short* __restrict__ h_bf, float* __restrict__ a_src,
                         float* __restrict__ a_dst, int N) {
    const int lane = threadIdx.x & 63;
    const int wave = threadIdx.x >> 6;
    const int r0 = blockIdx.x * 64 + wave * 16;
    const int lrow = lane & 15, lgrp = lane >> 4;
    const int arow = r0 + lrow;
    const bool ok = (arow < N);

    short8 afr[4];
    const float* xr = x + (size_t)arow * D + lgrp * 8;
#pragma unroll
    for (int kt = 0; kt < 4; ++kt) {
        if (ok) afr[kt] = load_bf8(xr + kt * 32);
        else { short8 zf; for (int j = 0; j < 8; ++j) zf[j] = 0; afr[kt] = zf; }
    }

    f32x4 acc[8];
#pragma unroll
    for (int f = 0; f < 8; ++f) acc[f] = (f32x4){0.f, 0.f, 0.f, 0.f};
#pragma unroll
    for (int f = 0; f < 8; ++f) {
        const short* wb = WgT + ((f * 16 + lrow) * D + lgrp * 8);
#pragma unroll
        for (int kt = 0; kt < 4; ++kt) {
            short8 b = *(const short8*)(wb + kt * 32);
            acc[f] = __builtin_amdgcn_mfma_f32_16x16x32_bf16(afr[kt], b, acc[f], 0, 0, 0);
        }
    }

    float ps[4] = {0.f, 0.f, 0.f, 0.f}, pd[4] = {0.f, 0.f, 0.f, 0.f};
    const int rbase = r0 + lgrp * 4;
#pragma unroll
    for (int f = 0; f < 8; ++f) {
        int col = f * 16 + lrow;
        float as = att_src[col], ad = att_dst[col];
#pragma unroll
        for (int j = 0; j < 4; ++j) {
            float v = acc[f][j];
            if (rbase + j < N) h_bf[(size_t)(rbase + j) * D + col] = f2bfu(v);
            ps[j] += v * as;
            pd[j] += v * ad;
        }
    }
#pragma unroll
    for (int m = 8; m >= 1; m >>= 1)
#pragma unroll
        for (int j = 0; j < 4; ++j) {
            ps[j] += __shfl_xor(ps[j], m);
            pd[j] += __shfl_xor(pd[j], m);
        }
    if (lrow == 0) {
#pragma unroll
        for (int j = 0; j < 4; ++j)
            if (rbase + j < N) { a_src[rbase + j] = ps[j]; a_dst[rbase + j] = pd[j]; }
    }
}

// ---- GAT aggregation: 16 lanes per dst node (4 nodes/wave), short8 row loads ----
__global__ void k_attn(const int* __restrict__ csr, const int* __restrict__ off,
                       const int* __restrict__ cnt, const float* __restrict__ a_src,
                       const float* __restrict__ a_dst, const unsigned short* __restrict__ h_bf,
                       const float* __restrict__ bg, unsigned short* __restrict__ hg_bf, int N) {
    const int lane = threadIdx.x & 63;
    const int l16 = lane & 15, grp = lane >> 4;
    const int gbase = grp << 4;
    const int d = blockIdx.x * 16 + ((threadIdx.x >> 6) << 2) + grp;
    if (d >= N) return;
    const int deg = cnt[d], o = off[d];
    const float ad = a_dst[d];
    float es = a_src[d] + ad;
    es = (es > 0.f) ? es : NEG_SLOPE * es;

    const int fo = l16 * 8;
    short8 hv = *(const short8*)(h_bf + (size_t)d * D + fo);
    float acc[8];
    float inv;

    if (deg <= 16) {
        int sv = 0;
        float e = -INFINITY;
        if (l16 < deg) {
            sv = csr[o + l16];
            float t = a_src[sv] + ad;
            e = (t > 0.f) ? t : NEG_SLOPE * t;
        }
        float mx = fmaxf(group_max16(e), es);
        float p = (l16 < deg) ? expf(e - mx) : 0.f;
        float pself = expf(es - mx);
        inv = 1.f / (group_sum16(p) + pself);
#pragma unroll
        for (int j = 0; j < 8; ++j) acc[j] = pself * bf2f((unsigned short)hv[j]);
        for (int i = 0; i < deg; ++i) {
            int s = __shfl(sv, gbase + i);
            float pi = __shfl(p, gbase + i);
            short8 row = *(const short8*)(h_bf + (size_t)s * D + fo);
#pragma unroll
            for (int j = 0; j < 8; ++j) acc[j] += pi * bf2f((unsigned short)row[j]);
        }
    } else {  // rare fallback
        float m2 = es;
        for (int i = l16; i < deg; i += 16) {
            float t = a_src[csr[o + i]] + ad;
            t = (t > 0.f) ? t : NEG_SLOPE * t;
            m2 = fmaxf(m2, t);
        }
        float mx = group_max16(m2);
        float zp = 0.f;
        for (int i = l16; i < deg; i += 16) {
            float t = a_src[csr[o + i]] + ad;
            t = (t > 0.f) ? t : NEG_SLOPE * t;
            zp += expf(t - mx);
        }
        float pself = expf(es - mx);
        inv = 1.f / (group_sum16(zp) + pself);
#pragma unroll
        for (int j = 0; j < 8; ++j) acc[j] = pself * bf2f((unsigned short)hv[j]);
        for (int i = 0; i < deg; ++i) {
            int s = csr[o + i];
            float t = a_src[s] + ad;
            t = (t > 0.f) ? t : NEG_SLOPE * t;
            float pi = expf(t - mx);
            short8 row = *(const short8*)(h_bf + (size_t)s * D + fo);
#pragma unroll
            for (int j = 0; j < 8; ++j) acc[j] += pi * bf2f((unsigned short)row[j]);
        }
    }
    short8 r;
#pragma unroll
    for (int j = 0; j < 8; ++j) r[j] = (short)f2bfu(acc[j] * inv + bg[fo + j]);
    *(short8*)(hg_bf + (size_t)d * D + fo) = r;
}

// ---- SAGE mean aggregation: 16 lanes per node, 4 nodes/wave ----
__global__ void k_sage(const int* __restrict__ csr, const int* __restrict__ off,
                       const int* __restrict__ cnt, const unsigned short* __restrict__ hg_bf,
                       unsigned short* __restrict__ mean_bf, int N) {
    const int lane = threadIdx.x & 63;
    const int l16 = lane & 15, grp = lane >> 4;
    const int gbase = grp << 4;
    const int d = blockIdx.x * 16 + ((threadIdx.x >> 6) << 2) + grp;
    if (d >= N) return;
    const int deg = cnt[d], o = off[d];
    const int fo = l16 * 8;
    float acc[8];
#pragma unroll
    for (int j = 0; j < 8; ++j) acc[j] = 0.f;
    if (deg <= 16) {
        int sv = 0;
        if (l16 < deg) sv = csr[o + l16];
        for (int i = 0; i < deg; ++i) {
            int s = __shfl(sv, gbase + i);
            short8 row = *(const short8*)(hg_bf + (size_t)s * D + fo);
#pragma unroll
            for (int j = 0; j < 8; ++j) acc[j] += bf2f((unsigned short)row[j]);
        }
    } else {
        for (int i = 0; i < deg; ++i) {
            int s = csr[o + i];
            short8 row = *(const short8*)(hg_bf + (size_t)s * D + fo);
#pragma unroll
            for (int j = 0; j < 8; ++j) acc[j] += bf2f((unsigned short)row[j]);
        }
    }
    const float inv = 1.f / fmaxf((float)deg, 1.f);
    short8 r;
#pragma unroll
    for (int j = 0; j < 8; ++j) r[j] = (short)f2bfu(acc[j] * inv);
    *(short8*)(mean_bf + (size_t)d * D + fo) = r;
}

// ---- out = normalize(mean@Wl + bl + hg@Wr) via MFMA bf16 ----
__global__ void k_out(const unsigned short* __restrict__ mean_bf,
                      const unsigned short* __restrict__ hg_bf,
                      const short* __restrict__ WlT, const short* __restrict__ WrT,
                      const float* __restrict__ bl, float* __restrict__ out, int N) {
    const int lane = threadIdx.x & 63;
    const int wave = threadIdx.x >> 6;
    const int r0 = blockIdx.x * 64 + wave * 16;
    const int lrow = lane & 15, lgrp = lane >> 4;
    const int arow = r0 + lrow;
    const bool ok = (arow < N);

    short8 am[4], ah[4];
    const unsigned short* mp = mean_bf + (size_t)arow * D + lgrp * 8;
    const unsigned short* hp = hg_bf + (size_t)arow * D + lgrp * 8;
#pragma unroll
    for (int kt = 0; kt < 4; ++kt) {
        if (ok) {
            am[kt] = *(const short8*)(mp + kt * 32);
            ah[kt] = *(const short8*)(hp + kt * 32);
        } else {
            short8 zf; for (int j = 0; j < 8; ++j) zf[j] = 0;
            am[kt] = zf; ah[kt] = zf;
        }
    }

    f32x4 acc[8];
#pragma unroll
    for (int f = 0; f < 8; ++f) {
        float b = bl[f * 16 + lrow];
        acc[f] = (f32x4){b, b, b, b};
    }
#pragma unroll
    for (int f = 0; f < 8; ++f) {
        const short* wl = WlT + ((f * 16 + lrow) * D + lgrp * 8);
        const short* wr = WrT + ((f * 16 + lrow) * D + lgrp * 8);
#pragma unroll
        for (int kt = 0; kt < 4; ++kt) {
            short8 b0 = *(const short8*)(wl + kt * 32);
            acc[f] = __builtin_amdgcn_mfma_f32_16x16x32_bf16(am[kt], b0, acc[f], 0, 0, 0);
            short8 b1 = *(const short8*)(wr + kt * 32);
            acc[f] = __builtin_amdgcn_mfma_f32_16x16x32_bf16(ah[kt], b1, acc[f], 0, 0, 0);
        }
    }

    float ss[4] = {0.f, 0.f, 0.f, 0.f};
#pragma unroll
    for (int f = 0; f < 8; ++f)
#pragma unroll
        for (int j = 0; j < 4; ++j) ss[j] += acc[f][j] * acc[f][j];
#pragma unroll
    for (int m = 8; m >= 1; m >>= 1)
#pragma unroll
        for (int j = 0; j < 4; ++j) ss[j] += __shfl_xor(ss[j], m);

    const int rbase = r0 + lgrp * 4;
#pragma unroll
    for (int j = 0; j < 4; ++j) {
        int r = rbase + j;
        if (r < N) {
            float sc = 1.f / fmaxf(sqrtf(ss[j]), 1e-12f);
#pragma unroll
            for (int f = 0; f < 8; ++f)
                out[(size_t)r * D + f * 16 + lrow] = acc[f][j] * sc;
        }
    }
}

extern "C" void kernel_launch(void* const* d_in, const int* in_sizes, int n_in,
                              void* d_out, int out_size, void* d_ws, size_t ws_size,
                              hipStream_t stream) {
    const float* x       = (const float*)d_in[0];
    const int*   ei      = (const int*)d_in[1];
    const float* Wg      = (const float*)d_in[2];
    const float* att_src = (const float*)d_in[3];
    const float* att_dst = (const float*)d_in[4];
    const float* bg      = (const float*)d_in[5];
    const float* Wl      = (const float*)d_in[6];
    const float* bl      = (const float*)d_in[7];
    const float* Wr      = (const float*)d_in[8];
    const int N = in_sizes[0] / D;
    const int E = in_sizes[1] / 2;

    char* w = (char*)d_ws;
    unsigned short* h_bf    = (unsigned short*)w;  w += (size_t)N * D * 2;
    unsigned short* hg_bf   = (unsigned short*)w;  w += (size_t)N * D * 2;
    unsigned short* mean_bf = (unsigned short*)w;  w += (size_t)N * D * 2;
    float* a_src = (float*)w;  w += (size_t)N * 4;
    float* a_dst = (float*)w;  w += (size_t)N * 4;
    int*   cnt_i = (int*)w;    w += (size_t)N * 4;
    int*   off   = (int*)w;    w += (size_t)N * 4;
    int*   fill  = (int*)w;    w += (size_t)N * 4;
    int*   btot  = (int*)w;    w += 1024 * 4;
    int*   csr   = (int*)w;    w += (size_t)E * 4;
    short* WgT   = (short*)w;  w += (size_t)D * D * 2;
    short* WlT   = (short*)w;  w += (size_t)D * D * 2;
    short* WrT   = (short*)w;  w += (size_t)D * D * 2;
    float* out_f = (float*)d_out;

    (void)hipMemsetAsync(cnt_i, 0, (size_t)N * 4, stream);
    (void)hipMemsetAsync(fill, 0, (size_t)N * 4, stream);

    const int nb = (N + SCAN_BS - 1) / SCAN_BS;

    k_wt<<<(3 * D * D) / 256, 256, 0, stream>>>(Wg, Wl, Wr, WgT, WlT, WrT);
    k_hist<<<(E + 255) / 256, 256, 0, stream>>>(ei, cnt_i, E);
    k_scan_block<<<nb, SCAN_BS, 0, stream>>>(cnt_i, off, btot, N);
    k_scan_tot<<<1, 1024, 0, stream>>>(btot, nb);
    k_scan_add<<<(N + 255) / 256, 256, 0, stream>>>(cnt_i, off, btot, N);
    k_bucket<<<(E + 255) / 256, 256, 0, stream>>>(ei, off, fill, csr, E);

    k_gemm_h<<<(N + 63) / 64, 256, 0, stream>>>(x, WgT, att_src, att_dst, h_bf, a_src, a_dst, N);
    k_attn<<<(N + 15) / 16, 256, 0, stream>>>(csr, off, cnt_i, a_src, a_dst, h_bf, bg, hg_bf, N);
    k_sage<<<(N + 15) / 16, 256, 0, stream>>>(csr, off, cnt_i, hg_bf, mean_bf, N);
    k_out<<<(N + 63) / 64, 256, 0, stream>>>(mean_bf, hg_bf, WlT, WrT, bl, out_f, N);
}

// Round 6
// 243.952 us; speedup vs baseline: 6.6752x; 1.0423x over previous
//
#include <hip/hip_runtime.h>
#include <hip/hip_bf16.h>

#define D 128
#define NEG_SLOPE 0.2f
#define SCAN_BS 512

typedef __attribute__((ext_vector_type(8))) short short8;
typedef __attribute__((ext_vector_type(4))) float f32x4;

__device__ __forceinline__ float group_max16(float v) {
#pragma unroll
    for (int m = 8; m >= 1; m >>= 1) v = fmaxf(v, __shfl_xor(v, m));
    return v;
}
__device__ __forceinline__ float group_sum16(float v) {
#pragma unroll
    for (int m = 8; m >= 1; m >>= 1) v += __shfl_xor(v, m);
    return v;
}

__device__ __forceinline__ unsigned short f2bfu(float f) {
    __hip_bfloat16 h = __float2bfloat16(f);
    return *reinterpret_cast<unsigned short*>(&h);
}

__device__ __forceinline__ float bf2f(unsigned short u) {
    return __uint_as_float(((unsigned)u) << 16);
}

__device__ __forceinline__ short8 load_bf8(const float* p) {
    float4 p0 = *(const float4*)p;
    float4 p1 = *(const float4*)(p + 4);
    short8 r;
    r[0] = (short)f2bfu(p0.x); r[1] = (short)f2bfu(p0.y);
    r[2] = (short)f2bfu(p0.z); r[3] = (short)f2bfu(p0.w);
    r[4] = (short)f2bfu(p1.x); r[5] = (short)f2bfu(p1.y);
    r[6] = (short)f2bfu(p1.z); r[7] = (short)f2bfu(p1.w);
    return r;
}

// transpose + convert the three 128x128 weight mats to bf16 (WT[n][k] = W[k][n])
__global__ void k_wt(const float* __restrict__ Wg, const float* __restrict__ Wl,
                     const float* __restrict__ Wr, short* __restrict__ WgT,
                     short* __restrict__ WlT, short* __restrict__ WrT) {
    int i = blockIdx.x * blockDim.x + threadIdx.x;
    int m = i >> 14;
    int r = (i >> 7) & 127;
    int c = i & 127;
    const float* src = (m == 0) ? Wg : (m == 1) ? Wl : Wr;
    short* dst = (m == 0) ? WgT : (m == 1) ? WlT : WrT;
    dst[r * D + c] = (short)f2bfu(src[c * D + r]);
}

// ---- CSR build ----
__global__ void k_hist(const int* __restrict__ ei, int* __restrict__ cnt, int E) {
    int i = blockIdx.x * blockDim.x + threadIdx.x;
    if (i < E) atomicAdd(&cnt[ei[E + i]], 1);
}

__global__ void k_scan_block(const int* __restrict__ cnt, int* __restrict__ incl,
                             int* __restrict__ btot, int N) {
    __shared__ int s[SCAN_BS];
    int t = threadIdx.x, i = blockIdx.x * SCAN_BS + t;
    int v = (i < N) ? cnt[i] : 0;
    s[t] = v;
    __syncthreads();
    for (int d = 1; d < SCAN_BS; d <<= 1) {
        int u = (t >= d) ? s[t - d] : 0;
        __syncthreads();
        s[t] += u;
        __syncthreads();
    }
    if (i < N) incl[i] = s[t];
    if (t == SCAN_BS - 1) btot[blockIdx.x] = s[t];
}

__global__ void k_scan_tot(int* __restrict__ btot, int nb) {
    __shared__ int s[1024];
    int t = threadIdx.x;
    int v = (t < nb) ? btot[t] : 0;
    s[t] = v;
    __syncthreads();
    for (int d = 1; d < 1024; d <<= 1) {
        int u = (t >= d) ? s[t - d] : 0;
        __syncthreads();
        s[t] += u;
        __syncthreads();
    }
    if (t < nb) btot[t] = s[t] - v;
}

__global__ void k_scan_add(const int* __restrict__ cnt, int* __restrict__ off,
                           const int* __restrict__ btot, int N) {
    int i = blockIdx.x * blockDim.x + threadIdx.x;
    if (i < N) off[i] = off[i] + btot[i / SCAN_BS] - cnt[i];
}

__global__ void k_bucket(const int* __restrict__ ei, const int* __restrict__ off,
                         int* __restrict__ fill, int* __restrict__ csr, int E) {
    int i = blockIdx.x * blockDim.x + threadIdx.x;
    if (i < E) {
        int dt = ei[E + i];
        int p = off[dt] + atomicAdd(&fill[dt], 1);
        csr[p] = ei[i];
    }
}

// ---- K1: h = x @ Wg (MFMA bf16) -> h_bf; a_src = h.att_src; a_dst = h.att_dst ----
__global__ void k_gemm_h(const float* __restrict__ x, const short* __restrict__ WgT,
                         const float* __restrict__ att_src, const float* __restrict__ att_dst,
                         unsigned short* __restrict__ h_bf, float* __restrict__ a_src,
                         float* __restrict__ a_dst, int N) {
    const int lane = threadIdx.x & 63;
    const int wave = threadIdx.x >> 6;
    const int r0 = blockIdx.x * 64 + wave * 16;
    const int lrow = lane & 15, lgrp = lane >> 4;
    const int arow = r0 + lrow;
    const bool ok = (arow < N);

    short8 afr[4];
    const float* xr = x + (size_t)arow * D + lgrp * 8;
#pragma unroll
    for (int kt = 0; kt < 4; ++kt) {
        if (ok) afr[kt] = load_bf8(xr + kt * 32);
        else { short8 zf; for (int j = 0; j < 8; ++j) zf[j] = 0; afr[kt] = zf; }
    }

    f32x4 acc[8];
#pragma unroll
    for (int f = 0; f < 8; ++f) acc[f] = (f32x4){0.f, 0.f, 0.f, 0.f};
#pragma unroll
    for (int f = 0; f < 8; ++f) {
        const short* wb = WgT + ((f * 16 + lrow) * D + lgrp * 8);
#pragma unroll
        for (int kt = 0; kt < 4; ++kt) {
            short8 b = *(const short8*)(wb + kt * 32);
            acc[f] = __builtin_amdgcn_mfma_f32_16x16x32_bf16(afr[kt], b, acc[f], 0, 0, 0);
        }
    }

    float ps[4] = {0.f, 0.f, 0.f, 0.f}, pd[4] = {0.f, 0.f, 0.f, 0.f};
    const int rbase = r0 + lgrp * 4;
#pragma unroll
    for (int f = 0; f < 8; ++f) {
        int col = f * 16 + lrow;
        float as = att_src[col], ad = att_dst[col];
#pragma unroll
        for (int j = 0; j < 4; ++j) {
            float v = acc[f][j];
            if (rbase + j < N) h_bf[(size_t)(rbase + j) * D + col] = f2bfu(v);
            ps[j] += v * as;
            pd[j] += v * ad;
        }
    }
#pragma unroll
    for (int m = 8; m >= 1; m >>= 1)
#pragma unroll
        for (int j = 0; j < 4; ++j) {
            ps[j] += __shfl_xor(ps[j], m);
            pd[j] += __shfl_xor(pd[j], m);
        }
    if (lrow == 0) {
#pragma unroll
        for (int j = 0; j < 4; ++j)
            if (rbase + j < N) { a_src[rbase + j] = ps[j]; a_dst[rbase + j] = pd[j]; }
    }
}

// ---- GAT aggregation: 16 lanes per dst node (4 nodes/wave), short8 row loads ----
__global__ void k_attn(const int* __restrict__ csr, const int* __restrict__ off,
                       const int* __restrict__ cnt, const float* __restrict__ a_src,
                       const float* __restrict__ a_dst, const unsigned short* __restrict__ h_bf,
                       const float* __restrict__ bg, unsigned short* __restrict__ hg_bf, int N) {
    const int lane = threadIdx.x & 63;
    const int l16 = lane & 15, grp = lane >> 4;
    const int gbase = grp << 4;
    const int d = blockIdx.x * 16 + ((threadIdx.x >> 6) << 2) + grp;
    if (d >= N) return;
    const int deg = cnt[d], o = off[d];
    const float ad = a_dst[d];
    float es = a_src[d] + ad;
    es = (es > 0.f) ? es : NEG_SLOPE * es;

    const int fo = l16 * 8;
    short8 hv = *(const short8*)(h_bf + (size_t)d * D + fo);
    float acc[8];
    float inv;

    if (deg <= 16) {
        int sv = 0;
        float e = -INFINITY;
        if (l16 < deg) {
            sv = csr[o + l16];
            float t = a_src[sv] + ad;
            e = (t > 0.f) ? t : NEG_SLOPE * t;
        }
        float mx = fmaxf(group_max16(e), es);
        float p = (l16 < deg) ? expf(e - mx) : 0.f;
        float pself = expf(es - mx);
        inv = 1.f / (group_sum16(p) + pself);
#pragma unroll
        for (int j = 0; j < 8; ++j) acc[j] = pself * bf2f((unsigned short)hv[j]);
        for (int i = 0; i < deg; ++i) {
            int s = __shfl(sv, gbase + i);
            float pi = __shfl(p, gbase + i);
            short8 row = *(const short8*)(h_bf + (size_t)s * D + fo);
#pragma unroll
            for (int j = 0; j < 8; ++j) acc[j] += pi * bf2f((unsigned short)row[j]);
        }
    } else {  // rare fallback
        float m2 = es;
        for (int i = l16; i < deg; i += 16) {
            float t = a_src[csr[o + i]] + ad;
            t = (t > 0.f) ? t : NEG_SLOPE * t;
            m2 = fmaxf(m2, t);
        }
        float mx = group_max16(m2);
        float zp = 0.f;
        for (int i = l16; i < deg; i += 16) {
            float t = a_src[csr[o + i]] + ad;
            t = (t > 0.f) ? t : NEG_SLOPE * t;
            zp += expf(t - mx);
        }
        float pself = expf(es - mx);
        inv = 1.f / (group_sum16(zp) + pself);
#pragma unroll
        for (int j = 0; j < 8; ++j) acc[j] = pself * bf2f((unsigned short)hv[j]);
        for (int i = 0; i < deg; ++i) {
            int s = csr[o + i];
            float t = a_src[s] + ad;
            t = (t > 0.f) ? t : NEG_SLOPE * t;
            float pi = expf(t - mx);
            short8 row = *(const short8*)(h_bf + (size_t)s * D + fo);
#pragma unroll
            for (int j = 0; j < 8; ++j) acc[j] += pi * bf2f((unsigned short)row[j]);
        }
    }
    short8 r;
#pragma unroll
    for (int j = 0; j < 8; ++j) r[j] = (short)f2bfu(acc[j] * inv + bg[fo + j]);
    *(short8*)(hg_bf + (size_t)d * D + fo) = r;
}

// ---- fused: SAGE mean (per-wave, into LDS) + out = normalize(mean@Wl + bl + hg@Wr) ----
__global__ void k_out(const int* __restrict__ csr, const int* __restrict__ off,
                      const int* __restrict__ cnt, const unsigned short* __restrict__ hg_bf,
                      const short* __restrict__ WlT, const short* __restrict__ WrT,
                      const float* __restrict__ bl, float* __restrict__ out, int N) {
    __shared__ unsigned short lds_mean[64 * D];   // 16 KB
    const int lane = threadIdx.x & 63;
    const int wave = threadIdx.x >> 6;
    const int r0 = blockIdx.x * 64;
    const int wr0 = wave * 16;

    // ---- phase 1: mean for this wave's 16 rows (16 lanes/node, 4 nodes/pass) ----
    {
        const int l16 = lane & 15, grp = lane >> 4;
        const int gbase = grp << 4;
        const int fo = l16 * 8;
#pragma unroll
        for (int p = 0; p < 4; ++p) {
            const int lrow_ = wr0 + p * 4 + grp;        // 0..63 within block
            const int d = r0 + lrow_;
            float acc[8];
#pragma unroll
            for (int j = 0; j < 8; ++j) acc[j] = 0.f;
            float inv = 0.f;
            if (d < N) {
                const int deg = cnt[d], o = off[d];
                if (deg <= 16) {
                    int sv = 0;
                    if (l16 < deg) sv = csr[o + l16];
                    for (int i = 0; i < deg; ++i) {
                        int s = __shfl(sv, gbase + i);
                        short8 row = *(const short8*)(hg_bf + (size_t)s * D + fo);
#pragma unroll
                        for (int j = 0; j < 8; ++j) acc[j] += bf2f((unsigned short)row[j]);
                    }
                } else {
                    for (int i = 0; i < deg; ++i) {
                        int s = csr[o + i];
                        short8 row = *(const short8*)(hg_bf + (size_t)s * D + fo);
#pragma unroll
                        for (int j = 0; j < 8; ++j) acc[j] += bf2f((unsigned short)row[j]);
                    }
                }
                inv = 1.f / fmaxf((float)deg, 1.f);
            }
            short8 r;
#pragma unroll
            for (int j = 0; j < 8; ++j) r[j] = (short)f2bfu(acc[j] * inv);
            *(short8*)(lds_mean + lrow_ * D + fo) = r;
        }
    }
    // no __syncthreads: each wave reads only the LDS rows it wrote

    // ---- phase 2: MFMA epilogue ----
    const int lrow = lane & 15, lgrp = lane >> 4;
    const int arow = r0 + wr0 + lrow;
    const bool ok = (arow < N);

    short8 am[4], ah[4];
    const unsigned short* mp = lds_mean + (wr0 + lrow) * D + lgrp * 8;
    const unsigned short* hp = hg_bf + (size_t)arow * D + lgrp * 8;
#pragma unroll
    for (int kt = 0; kt < 4; ++kt) {
        am[kt] = *(const short8*)(mp + kt * 32);
        if (ok) ah[kt] = *(const short8*)(hp + kt * 32);
        else { short8 zf; for (int j = 0; j < 8; ++j) zf[j] = 0; ah[kt] = zf; }
    }

    f32x4 acc[8];
#pragma unroll
    for (int f = 0; f < 8; ++f) {
        float b = bl[f * 16 + lrow];
        acc[f] = (f32x4){b, b, b, b};
    }
#pragma unroll
    for (int f = 0; f < 8; ++f) {
        const short* wl = WlT + ((f * 16 + lrow) * D + lgrp * 8);
        const short* wr = WrT + ((f * 16 + lrow) * D + lgrp * 8);
#pragma unroll
        for (int kt = 0; kt < 4; ++kt) {
            short8 b0 = *(const short8*)(wl + kt * 32);
            acc[f] = __builtin_amdgcn_mfma_f32_16x16x32_bf16(am[kt], b0, acc[f], 0, 0, 0);
            short8 b1 = *(const short8*)(wr + kt * 32);
            acc[f] = __builtin_amdgcn_mfma_f32_16x16x32_bf16(ah[kt], b1, acc[f], 0, 0, 0);
        }
    }

    float ss[4] = {0.f, 0.f, 0.f, 0.f};
#pragma unroll
    for (int f = 0; f < 8; ++f)
#pragma unroll
        for (int j = 0; j < 4; ++j) ss[j] += acc[f][j] * acc[f][j];
#pragma unroll
    for (int m = 8; m >= 1; m >>= 1)
#pragma unroll
        for (int j = 0; j < 4; ++j) ss[j] += __shfl_xor(ss[j], m);

    const int rbase = r0 + wr0 + lgrp * 4;
#pragma unroll
    for (int j = 0; j < 4; ++j) {
        int r = rbase + j;
        if (r < N) {
            float sc = 1.f / fmaxf(sqrtf(ss[j]), 1e-12f);
#pragma unroll
            for (int f = 0; f < 8; ++f)
                out[(size_t)r * D + f * 16 + lrow] = acc[f][j] * sc;
        }
    }
}

extern "C" void kernel_launch(void* const* d_in, const int* in_sizes, int n_in,
                              void* d_out, int out_size, void* d_ws, size_t ws_size,
                              hipStream_t stream) {
    const float* x       = (const float*)d_in[0];
    const int*   ei      = (const int*)d_in[1];
    const float* Wg      = (const float*)d_in[2];
    const float* att_src = (const float*)d_in[3];
    const float* att_dst = (const float*)d_in[4];
    const float* bg      = (const float*)d_in[5];
    const float* Wl      = (const float*)d_in[6];
    const float* bl      = (const float*)d_in[7];
    const float* Wr      = (const float*)d_in[8];
    const int N = in_sizes[0] / D;
    const int E = in_sizes[1] / 2;

    char* w = (char*)d_ws;
    unsigned short* h_bf  = (unsigned short*)w;  w += (size_t)N * D * 2;
    unsigned short* hg_bf = (unsigned short*)w;  w += (size_t)N * D * 2;
    float* a_src = (float*)w;  w += (size_t)N * 4;
    float* a_dst = (float*)w;  w += (size_t)N * 4;
    int*   cnt_i = (int*)w;    w += (size_t)N * 4;
    int*   off   = (int*)w;    w += (size_t)N * 4;
    int*   fill  = (int*)w;    w += (size_t)N * 4;
    int*   btot  = (int*)w;    w += 1024 * 4;
    int*   csr   = (int*)w;    w += (size_t)E * 4;
    short* WgT   = (short*)w;  w += (size_t)D * D * 2;
    short* WlT   = (short*)w;  w += (size_t)D * D * 2;
    short* WrT   = (short*)w;  w += (size_t)D * D * 2;
    float* out_f = (float*)d_out;

    (void)hipMemsetAsync(cnt_i, 0, (size_t)N * 4, stream);
    (void)hipMemsetAsync(fill, 0, (size_t)N * 4, stream);

    const int nb = (N + SCAN_BS - 1) / SCAN_BS;

    k_wt<<<(3 * D * D) / 256, 256, 0, stream>>>(Wg, Wl, Wr, WgT, WlT, WrT);
    k_hist<<<(E + 255) / 256, 256, 0, stream>>>(ei, cnt_i, E);
    k_scan_block<<<nb, SCAN_BS, 0, stream>>>(cnt_i, off, btot, N);
    k_scan_tot<<<1, 1024, 0, stream>>>(btot, nb);
    k_scan_add<<<(N + 255) / 256, 256, 0, stream>>>(cnt_i, off, btot, N);
    k_bucket<<<(E + 255) / 256, 256, 0, stream>>>(ei, off, fill, csr, E);

    k_gemm_h<<<(N + 63) / 64, 256, 0, stream>>>(x, WgT, att_src, att_dst, h_bf, a_src, a_dst, N);
    k_attn<<<(N + 15) / 16, 256, 0, stream>>>(csr, off, cnt_i, a_src, a_dst, h_bf, bg, hg_bf, N);
    k_out<<<(N + 63) / 64, 256, 0, stream>>>(csr, off, cnt_i, hg_bf, WlT, WrT, bl, out_f, N);
}

// Round 7
// 236.149 us; speedup vs baseline: 6.8958x; 1.0330x over previous
//
#include <hip/hip_runtime.h>
#include <hip/hip_bf16.h>

#define D 128
#define NEG_SLOPE 0.2f
#define SCAN_BS 512

typedef __attribute__((ext_vector_type(8))) short short8;
typedef __attribute__((ext_vector_type(4))) float f32x4;

__device__ __forceinline__ float group_max16(float v) {
#pragma unroll
    for (int m = 8; m >= 1; m >>= 1) v = fmaxf(v, __shfl_xor(v, m));
    return v;
}
__device__ __forceinline__ float group_sum16(float v) {
#pragma unroll
    for (int m = 8; m >= 1; m >>= 1) v += __shfl_xor(v, m);
    return v;
}

__device__ __forceinline__ unsigned short f2bfu(float f) {
    __hip_bfloat16 h = __float2bfloat16(f);
    return *reinterpret_cast<unsigned short*>(&h);
}

__device__ __forceinline__ float bf2f(unsigned short u) {
    return __uint_as_float(((unsigned)u) << 16);
}

__device__ __forceinline__ short8 load_bf8(const float* p) {
    float4 p0 = *(const float4*)p;
    float4 p1 = *(const float4*)(p + 4);
    short8 r;
    r[0] = (short)f2bfu(p0.x); r[1] = (short)f2bfu(p0.y);
    r[2] = (short)f2bfu(p0.z); r[3] = (short)f2bfu(p0.w);
    r[4] = (short)f2bfu(p1.x); r[5] = (short)f2bfu(p1.y);
    r[6] = (short)f2bfu(p1.z); r[7] = (short)f2bfu(p1.w);
    return r;
}

// transpose + convert the three 128x128 weight mats to bf16 (WT[n][k] = W[k][n])
__global__ void k_wt(const float* __restrict__ Wg, const float* __restrict__ Wl,
                     const float* __restrict__ Wr, short* __restrict__ WgT,
                     short* __restrict__ WlT, short* __restrict__ WrT) {
    int i = blockIdx.x * blockDim.x + threadIdx.x;
    int m = i >> 14;
    int r = (i >> 7) & 127;
    int c = i & 127;
    const float* src = (m == 0) ? Wg : (m == 1) ? Wl : Wr;
    short* dst = (m == 0) ? WgT : (m == 1) ? WlT : WrT;
    dst[r * D + c] = (short)f2bfu(src[c * D + r]);
}

// ---- CSR build ----
__global__ void k_hist(const int* __restrict__ ei, int* __restrict__ cnt, int E) {
    int i = blockIdx.x * blockDim.x + threadIdx.x;
    if (i < E) atomicAdd(&cnt[ei[E + i]], 1);
}

__global__ void k_scan_block(const int* __restrict__ cnt, int* __restrict__ incl,
                             int* __restrict__ btot, int N) {
    __shared__ int s[SCAN_BS];
    int t = threadIdx.x, i = blockIdx.x * SCAN_BS + t;
    int v = (i < N) ? cnt[i] : 0;
    s[t] = v;
    __syncthreads();
    for (int d = 1; d < SCAN_BS; d <<= 1) {
        int u = (t >= d) ? s[t - d] : 0;
        __syncthreads();
        s[t] += u;
        __syncthreads();
    }
    if (i < N) incl[i] = s[t];
    if (t == SCAN_BS - 1) btot[blockIdx.x] = s[t];
}

__global__ void k_scan_tot(int* __restrict__ btot, int nb) {
    __shared__ int s[1024];
    int t = threadIdx.x;
    int v = (t < nb) ? btot[t] : 0;
    s[t] = v;
    __syncthreads();
    for (int d = 1; d < 1024; d <<= 1) {
        int u = (t >= d) ? s[t - d] : 0;
        __syncthreads();
        s[t] += u;
        __syncthreads();
    }
    if (t < nb) btot[t] = s[t] - v;
}

__global__ void k_scan_add(const int* __restrict__ cnt, int* __restrict__ off,
                           const int* __restrict__ btot, int N) {
    int i = blockIdx.x * blockDim.x + threadIdx.x;
    if (i < N) off[i] = off[i] + btot[i / SCAN_BS] - cnt[i];
}

__global__ void k_bucket(const int* __restrict__ ei, const int* __restrict__ off,
                         int* __restrict__ fill, int* __restrict__ csr, int E) {
    int i = blockIdx.x * blockDim.x + threadIdx.x;
    if (i < E) {
        int dt = ei[E + i];
        int p = off[dt] + atomicAdd(&fill[dt], 1);
        csr[p] = ei[i];
    }
}

// ---- K1: h = x @ Wg (MFMA bf16) -> h_bf; a_src = h.att_src; a_dst = h.att_dst ----
__global__ void k_gemm_h(const float* __restrict__ x, const short* __restrict__ WgT,
                         const float* __restrict__ att_src, const float* __restrict__ att_dst,
                         unsigned short* __restrict__ h_bf, float* __restrict__ a_src,
                         float* __restrict__ a_dst, int N) {
    const int lane = threadIdx.x & 63;
    const int wave = threadIdx.x >> 6;
    const int r0 = blockIdx.x * 64 + wave * 16;
    const int lrow = lane & 15, lgrp = lane >> 4;
    const int arow = r0 + lrow;
    const bool ok = (arow < N);

    short8 afr[4];
    const float* xr = x + (size_t)arow * D + lgrp * 8;
#pragma unroll
    for (int kt = 0; kt < 4; ++kt) {
        if (ok) afr[kt] = load_bf8(xr + kt * 32);
        else { short8 zf; for (int j = 0; j < 8; ++j) zf[j] = 0; afr[kt] = zf; }
    }

    f32x4 acc[8];
#pragma unroll
    for (int f = 0; f < 8; ++f) acc[f] = (f32x4){0.f, 0.f, 0.f, 0.f};
#pragma unroll
    for (int f = 0; f < 8; ++f) {
        const short* wb = WgT + ((f * 16 + lrow) * D + lgrp * 8);
#pragma unroll
        for (int kt = 0; kt < 4; ++kt) {
            short8 b = *(const short8*)(wb + kt * 32);
            acc[f] = __builtin_amdgcn_mfma_f32_16x16x32_bf16(afr[kt], b, acc[f], 0, 0, 0);
        }
    }

    float ps[4] = {0.f, 0.f, 0.f, 0.f}, pd[4] = {0.f, 0.f, 0.f, 0.f};
    const int rbase = r0 + lgrp * 4;
#pragma unroll
    for (int f = 0; f < 8; ++f) {
        int col = f * 16 + lrow;
        float as = att_src[col], ad = att_dst[col];
#pragma unroll
        for (int j = 0; j < 4; ++j) {
            float v = acc[f][j];
            if (rbase + j < N) h_bf[(size_t)(rbase + j) * D + col] = f2bfu(v);
            ps[j] += v * as;
            pd[j] += v * ad;
        }
    }
#pragma unroll
    for (int m = 8; m >= 1; m >>= 1)
#pragma unroll
        for (int j = 0; j < 4; ++j) {
            ps[j] += __shfl_xor(ps[j], m);
            pd[j] += __shfl_xor(pd[j], m);
        }
    if (lrow == 0) {
#pragma unroll
        for (int j = 0; j < 4; ++j)
            if (rbase + j < N) { a_src[rbase + j] = ps[j]; a_dst[rbase + j] = pd[j]; }
    }
}

// ---- GAT aggregation: 16 lanes per dst node (4 nodes/wave), 4-way MLP unroll ----
__global__ void k_attn(const int* __restrict__ csr, const int* __restrict__ off,
                       const int* __restrict__ cnt, const float* __restrict__ a_src,
                       const float* __restrict__ a_dst, const unsigned short* __restrict__ h_bf,
                       const float* __restrict__ bg, unsigned short* __restrict__ hg_bf, int N) {
    const int lane = threadIdx.x & 63;
    const int l16 = lane & 15, grp = lane >> 4;
    const int gbase = grp << 4;
    const int d = blockIdx.x * 16 + ((threadIdx.x >> 6) << 2) + grp;
    if (d >= N) return;
    const int deg = cnt[d], o = off[d];
    const float ad = a_dst[d];
    float es = a_src[d] + ad;
    es = (es > 0.f) ? es : NEG_SLOPE * es;

    const int fo = l16 * 8;
    short8 hv = *(const short8*)(h_bf + (size_t)d * D + fo);
    float acc[8];
    float inv;

    if (deg <= 16) {
        int sv = 0;
        float e = -INFINITY;
        if (l16 < deg) {
            sv = csr[o + l16];
            float t = a_src[sv] + ad;
            e = (t > 0.f) ? t : NEG_SLOPE * t;
        }
        float mx = fmaxf(group_max16(e), es);
        float p = (l16 < deg) ? expf(e - mx) : 0.f;
        float pself = expf(es - mx);
        inv = 1.f / (group_sum16(p) + pself);
#pragma unroll
        for (int j = 0; j < 8; ++j) acc[j] = pself * bf2f((unsigned short)hv[j]);
        int i = 0;
        for (; i + 4 <= deg; i += 4) {
            int s0 = __shfl(sv, gbase + i);
            int s1 = __shfl(sv, gbase + i + 1);
            int s2 = __shfl(sv, gbase + i + 2);
            int s3 = __shfl(sv, gbase + i + 3);
            float p0 = __shfl(p, gbase + i);
            float p1 = __shfl(p, gbase + i + 1);
            float p2 = __shfl(p, gbase + i + 2);
            float p3 = __shfl(p, gbase + i + 3);
            short8 r0 = *(const short8*)(h_bf + (size_t)s0 * D + fo);
            short8 r1 = *(const short8*)(h_bf + (size_t)s1 * D + fo);
            short8 r2 = *(const short8*)(h_bf + (size_t)s2 * D + fo);
            short8 r3 = *(const short8*)(h_bf + (size_t)s3 * D + fo);
#pragma unroll
            for (int j = 0; j < 8; ++j)
                acc[j] += p0 * bf2f((unsigned short)r0[j]) + p1 * bf2f((unsigned short)r1[j])
                        + p2 * bf2f((unsigned short)r2[j]) + p3 * bf2f((unsigned short)r3[j]);
        }
        for (; i < deg; ++i) {
            int s = __shfl(sv, gbase + i);
            float pi = __shfl(p, gbase + i);
            short8 row = *(const short8*)(h_bf + (size_t)s * D + fo);
#pragma unroll
            for (int j = 0; j < 8; ++j) acc[j] += pi * bf2f((unsigned short)row[j]);
        }
    } else {  // rare fallback
        float m2 = es;
        for (int i = l16; i < deg; i += 16) {
            float t = a_src[csr[o + i]] + ad;
            t = (t > 0.f) ? t : NEG_SLOPE * t;
            m2 = fmaxf(m2, t);
        }
        float mx = group_max16(m2);
        float zp = 0.f;
        for (int i = l16; i < deg; i += 16) {
            float t = a_src[csr[o + i]] + ad;
            t = (t > 0.f) ? t : NEG_SLOPE * t;
            zp += expf(t - mx);
        }
        float pself = expf(es - mx);
        inv = 1.f / (group_sum16(zp) + pself);
#pragma unroll
        for (int j = 0; j < 8; ++j) acc[j] = pself * bf2f((unsigned short)hv[j]);
        for (int i = 0; i < deg; ++i) {
            int s = csr[o + i];
            float t = a_src[s] + ad;
            t = (t > 0.f) ? t : NEG_SLOPE * t;
            float pi = expf(t - mx);
            short8 row = *(const short8*)(h_bf + (size_t)s * D + fo);
#pragma unroll
            for (int j = 0; j < 8; ++j) acc[j] += pi * bf2f((unsigned short)row[j]);
        }
    }
    short8 r;
#pragma unroll
    for (int j = 0; j < 8; ++j) r[j] = (short)f2bfu(acc[j] * inv + bg[fo + j]);
    *(short8*)(hg_bf + (size_t)d * D + fo) = r;
}

// ---- fused: SAGE mean (per-wave, into LDS) + out = normalize(mean@Wl + bl + hg@Wr) ----
__global__ void k_out(const int* __restrict__ csr, const int* __restrict__ off,
                      const int* __restrict__ cnt, const unsigned short* __restrict__ hg_bf,
                      const short* __restrict__ WlT, const short* __restrict__ WrT,
                      const float* __restrict__ bl, float* __restrict__ out, int N) {
    __shared__ unsigned short lds_mean[64 * D];   // 16 KB
    const int lane = threadIdx.x & 63;
    const int wave = threadIdx.x >> 6;
    const int r0 = blockIdx.x * 64;
    const int wr0 = wave * 16;
    const int lrow = lane & 15, lgrp = lane >> 4;
    const int arow = r0 + wr0 + lrow;
    const bool ok = (arow < N);

    // hoist phase-2 global loads so they overlap the gather latency
    short8 ah[4];
    {
        const unsigned short* hp = hg_bf + (size_t)arow * D + lgrp * 8;
#pragma unroll
        for (int kt = 0; kt < 4; ++kt) {
            if (ok) ah[kt] = *(const short8*)(hp + kt * 32);
            else { short8 zf; for (int j = 0; j < 8; ++j) zf[j] = 0; ah[kt] = zf; }
        }
    }
    f32x4 acc[8];
#pragma unroll
    for (int f = 0; f < 8; ++f) {
        float b = bl[f * 16 + lrow];
        acc[f] = (f32x4){b, b, b, b};
    }

    // ---- phase 1: mean for this wave's 16 rows (16 lanes/node, 4 nodes/pass) ----
    {
        const int l16 = lane & 15, grp = lane >> 4;
        const int gbase = grp << 4;
        const int fo = l16 * 8;
#pragma unroll
        for (int p = 0; p < 4; ++p) {
            const int lrow_ = wr0 + p * 4 + grp;        // 0..63 within block
            const int d = r0 + lrow_;
            float macc[8];
#pragma unroll
            for (int j = 0; j < 8; ++j) macc[j] = 0.f;
            float minv = 0.f;
            if (d < N) {
                const int deg = cnt[d], o = off[d];
                if (deg <= 16) {
                    int sv = 0;
                    if (l16 < deg) sv = csr[o + l16];
                    int i = 0;
                    for (; i + 4 <= deg; i += 4) {
                        int s0 = __shfl(sv, gbase + i);
                        int s1 = __shfl(sv, gbase + i + 1);
                        int s2 = __shfl(sv, gbase + i + 2);
                        int s3 = __shfl(sv, gbase + i + 3);
                        short8 r0_ = *(const short8*)(hg_bf + (size_t)s0 * D + fo);
                        short8 r1_ = *(const short8*)(hg_bf + (size_t)s1 * D + fo);
                        short8 r2_ = *(const short8*)(hg_bf + (size_t)s2 * D + fo);
                        short8 r3_ = *(const short8*)(hg_bf + (size_t)s3 * D + fo);
#pragma unroll
                        for (int j = 0; j < 8; ++j)
                            macc[j] += bf2f((unsigned short)r0_[j]) + bf2f((unsigned short)r1_[j])
                                     + bf2f((unsigned short)r2_[j]) + bf2f((unsigned short)r3_[j]);
                    }
                    for (; i < deg; ++i) {
                        int s = __shfl(sv, gbase + i);
                        short8 row = *(const short8*)(hg_bf + (size_t)s * D + fo);
#pragma unroll
                        for (int j = 0; j < 8; ++j) macc[j] += bf2f((unsigned short)row[j]);
                    }
                } else {
                    for (int i = 0; i < deg; ++i) {
                        int s = csr[o + i];
                        short8 row = *(const short8*)(hg_bf + (size_t)s * D + fo);
#pragma unroll
                        for (int j = 0; j < 8; ++j) macc[j] += bf2f((unsigned short)row[j]);
                    }
                }
                minv = 1.f / fmaxf((float)deg, 1.f);
            }
            short8 r;
#pragma unroll
            for (int j = 0; j < 8; ++j) r[j] = (short)f2bfu(macc[j] * minv);
            *(short8*)(lds_mean + lrow_ * D + fo) = r;
        }
    }
    // no __syncthreads: each wave reads only the LDS rows it wrote

    // ---- phase 2: MFMA epilogue ----
    short8 am[4];
    const unsigned short* mp = lds_mean + (wr0 + lrow) * D + lgrp * 8;
#pragma unroll
    for (int kt = 0; kt < 4; ++kt) am[kt] = *(const short8*)(mp + kt * 32);

#pragma unroll
    for (int f = 0; f < 8; ++f) {
        const short* wl = WlT + ((f * 16 + lrow) * D + lgrp * 8);
        const short* wr = WrT + ((f * 16 + lrow) * D + lgrp * 8);
#pragma unroll
        for (int kt = 0; kt < 4; ++kt) {
            short8 b0 = *(const short8*)(wl + kt * 32);
            acc[f] = __builtin_amdgcn_mfma_f32_16x16x32_bf16(am[kt], b0, acc[f], 0, 0, 0);
            short8 b1 = *(const short8*)(wr + kt * 32);
            acc[f] = __builtin_amdgcn_mfma_f32_16x16x32_bf16(ah[kt], b1, acc[f], 0, 0, 0);
        }
    }

    float ss[4] = {0.f, 0.f, 0.f, 0.f};
#pragma unroll
    for (int f = 0; f < 8; ++f)
#pragma unroll
        for (int j = 0; j < 4; ++j) ss[j] += acc[f][j] * acc[f][j];
#pragma unroll
    for (int m = 8; m >= 1; m >>= 1)
#pragma unroll
        for (int j = 0; j < 4; ++j) ss[j] += __shfl_xor(ss[j], m);

    const int rbase = r0 + wr0 + lgrp * 4;
#pragma unroll
    for (int j = 0; j < 4; ++j) {
        int r = rbase + j;
        if (r < N) {
            float sc = 1.f / fmaxf(sqrtf(ss[j]), 1e-12f);
#pragma unroll
            for (int f = 0; f < 8; ++f)
                out[(size_t)r * D + f * 16 + lrow] = acc[f][j] * sc;
        }
    }
}

extern "C" void kernel_launch(void* const* d_in, const int* in_sizes, int n_in,
                              void* d_out, int out_size, void* d_ws, size_t ws_size,
                              hipStream_t stream) {
    const float* x       = (const float*)d_in[0];
    const int*   ei      = (const int*)d_in[1];
    const float* Wg      = (const float*)d_in[2];
    const float* att_src = (const float*)d_in[3];
    const float* att_dst = (const float*)d_in[4];
    const float* bg      = (const float*)d_in[5];
    const float* Wl      = (const float*)d_in[6];
    const float* bl      = (const float*)d_in[7];
    const float* Wr      = (const float*)d_in[8];
    const int N = in_sizes[0] / D;
    const int E = in_sizes[1] / 2;

    char* w = (char*)d_ws;
    unsigned short* h_bf  = (unsigned short*)w;  w += (size_t)N * D * 2;
    unsigned short* hg_bf = (unsigned short*)w;  w += (size_t)N * D * 2;
    float* a_src = (float*)w;  w += (size_t)N * 4;
    float* a_dst = (float*)w;  w += (size_t)N * 4;
    int*   cnt_i = (int*)w;    w += (size_t)N * 4;
    int*   off   = (int*)w;    w += (size_t)N * 4;
    int*   fill  = (int*)w;    w += (size_t)N * 4;
    int*   btot  = (int*)w;    w += 1024 * 4;
    int*   csr   = (int*)w;    w += (size_t)E * 4;
    short* WgT   = (short*)w;  w += (size_t)D * D * 2;
    short* WlT   = (short*)w;  w += (size_t)D * D * 2;
    short* WrT   = (short*)w;  w += (size_t)D * D * 2;
    float* out_f = (float*)d_out;

    (void)hipMemsetAsync(cnt_i, 0, (size_t)N * 4, stream);
    (void)hipMemsetAsync(fill, 0, (size_t)N * 4, stream);

    const int nb = (N + SCAN_BS - 1) / SCAN_BS;

    k_wt<<<(3 * D * D) / 256, 256, 0, stream>>>(Wg, Wl, Wr, WgT, WlT, WrT);
    k_hist<<<(E + 255) / 256, 256, 0, stream>>>(ei, cnt_i, E);
    k_scan_block<<<nb, SCAN_BS, 0, stream>>>(cnt_i, off, btot, N);
    k_scan_tot<<<1, 1024, 0, stream>>>(btot, nb);
    k_scan_add<<<(N + 255) / 256, 256, 0, stream>>>(cnt_i, off, btot, N);
    k_bucket<<<(E + 255) / 256, 256, 0, stream>>>(ei, off, fill, csr, E);

    k_gemm_h<<<(N + 63) / 64, 256, 0, stream>>>(x, WgT, att_src, att_dst, h_bf, a_src, a_dst, N);
    k_attn<<<(N + 15) / 16, 256, 0, stream>>>(csr, off, cnt_i, a_src, a_dst, h_bf, bg, hg_bf, N);
    k_out<<<(N + 63) / 64, 256, 0, stream>>>(csr, off, cnt_i, hg_bf, WlT, WrT, bl, out_f, N);
}